// Round 6
// baseline (1045.490 us; speedup 1.0000x reference)
//
#include <hip/hip_runtime.h>
#include <math.h>

#define Cc 32
#define Hc 128
#define Wc 160
#define Dc 48
#define HWc (Hc*Wc)
#define TS 16
#define HALO (TS+2)           // 18
#define NPOS (HALO*HALO)      // 324
#define DCHUNK 8
#define NCHUNK (Dc/DCHUNK)    // 6
#define VSTR4 11              // var position stride in float4 (44 floats; 12p%32 bank walk)
#define PSTR4 3               // param stride in float4 (cw0, cw1, idx-pack)
#define NPASS 6               // ceil(NPOS / 64 groups)

typedef float v2f __attribute__((ext_vector_type(2)));
static __device__ __forceinline__ v2f vfma2(v2f a, v2f b, v2f c) { return __builtin_elementwise_fma(a, b, c); }
static __device__ __forceinline__ v2f vlo(float4 v) { v2f r; r.x = v.x; r.y = v.y; return r; }
static __device__ __forceinline__ v2f vhi(float4 v) { v2f r; r.x = v.z; r.y = v.w; return r; }
static __device__ __forceinline__ v2f vbc(float s) { v2f r; r.x = s; r.y = s; return r; }

// ---------------- kernel 1: transpose CHW->HWC + proj matrices + weight repack ----------------
__global__ void k_pre(const float* __restrict__ f0, const float* __restrict__ f1,
                      const float* __restrict__ f2, const float* __restrict__ proj,
                      const float* __restrict__ wreg,
                      float* __restrict__ o0, float* __restrict__ o1, float* __restrict__ o2,
                      float* __restrict__ wsproj, float* __restrict__ w2) {
    const int tid = threadIdx.x;
    const int p = blockIdx.x * 256 + tid;
    if (p < HWc) {
        const float* f = (blockIdx.y == 0) ? f0 : (blockIdx.y == 1) ? f1 : f2;
        float*       o = (blockIdx.y == 0) ? o0 : (blockIdx.y == 1) ? o1 : o2;
        float v[Cc];
#pragma unroll
        for (int c = 0; c < Cc; c++) v[c] = f[c * HWc + p];   // coalesced across lanes
        float4* o4 = (float4*)(o + (size_t)p * Cc);
#pragma unroll
        for (int j = 0; j < 8; j++)
            o4[j] = make_float4(v[4 * j], v[4 * j + 1], v[4 * j + 2], v[4 * j + 3]);
    }
    if (blockIdx.x == 0 && blockIdx.y == 0) {
        // weight repack: w2[half(2)][khkw(9)][kd(3)][c(16)]
        for (int i = tid; i < 2 * 9 * 3 * 16; i += 256) {
            int c = i & 15;
            int t = i >> 4;
            int kd = t % 3;
            int t2 = t / 3;
            int khkw = t2 % 9;
            int half = t2 / 9;
            int ch = half * 16 + c;
            w2[i] = wreg[ch * 27 + kd * 9 + khkw];
        }
        if (tid == 0) {
            float a[4][8];
            for (int i = 0; i < 4; i++)
                for (int j = 0; j < 4; j++) {
                    a[i][j]     = proj[i * 4 + j];
                    a[i][j + 4] = (i == j) ? 1.f : 0.f;
                }
            for (int col = 0; col < 4; col++) {
                int piv = col; float best = fabsf(a[col][col]);
                for (int r = col + 1; r < 4; r++) {
                    float v = fabsf(a[r][col]);
                    if (v > best) { best = v; piv = r; }
                }
                if (piv != col)
                    for (int j = 0; j < 8; j++) { float t = a[col][j]; a[col][j] = a[piv][j]; a[piv][j] = t; }
                float inv = 1.f / a[col][col];
                for (int j = 0; j < 8; j++) a[col][j] *= inv;
                for (int r = 0; r < 4; r++) if (r != col) {
                    float f = a[r][col];
                    for (int j = 0; j < 8; j++) a[r][j] -= f * a[col][j];
                }
            }
            for (int v = 1; v < 3; v++) {
                const float* P = proj + v * 16;
                float M[3][4];
                for (int i = 0; i < 3; i++)
                    for (int j = 0; j < 4; j++) {
                        float s = 0.f;
                        for (int k = 0; k < 4; k++) s += P[i * 4 + k] * a[k][4 + j];
                        M[i][j] = s;
                    }
                float* o = wsproj + (v - 1) * 12;
                o[0] = M[0][0]; o[1] = M[0][1]; o[2] = M[0][2];
                o[3] = M[1][0]; o[4] = M[1][1]; o[5] = M[1][2];
                o[6] = M[2][0]; o[7] = M[2][1]; o[8] = M[2][2];
                o[9] = M[0][3]; o[10] = M[1][3]; o[11] = M[2][3];
            }
        }
    }
}

// ---------------- kernel 2: fused warp + variance + 3D conv, 512-thread merged block ----------------
// R6: both channel halves in one 512-thr block -> grid 480 = single generation
// (R5's 960 blocks @3/CU had a 192-block 25%-fill tail). Phase A params shared
// across halves; ref gathers hoisted out of the depth loop; float2-packed math
// targets v_pk_fma_f32. Spill guard: WRITE_SIZE must stay ~7.7MB (R2 failure mode).
__global__ __launch_bounds__(512, 4) void k_cost(
    const float* __restrict__ fT0, const float* __restrict__ fT1, const float* __restrict__ fT2,
    const float* __restrict__ dvals, const float4* __restrict__ w2_4,
    const float* __restrict__ wsproj, float* __restrict__ costvol)
{
    __shared__ float4 var_l[NPOS * VSTR4];   // 57024 B
    __shared__ float4 par_l[NPOS * PSTR4];   // 15552 B
    __shared__ float projl[24];

    const int tid = threadIdx.x;
    if (tid < 24) projl[tid] = wsproj[tid];
    __syncthreads();

    const int tileX = blockIdx.x;                 // 0..9
    const int tileY = blockIdx.y;                 // 0..7
    const int d0    = blockIdx.z * DCHUNK;
    const int tidh = tid & 255;                   // pixel id within tile
    const int hf   = tid >> 8;                    // channel half (0/1)
    const int tx = tidh & 15, ty = tidh >> 4;
    const int baseH = tileY * TS - 1, baseW = tileX * TS - 1;

    const int g = tid >> 3;                       // gather group (0..63)
    const int e = tid & 7;                        // float4 slot within 32-ch record

    const float4* fT0_4 = (const float4*)fT0;
    const float4* fT1_4 = (const float4*)fT1;
    const float4* fT2_4 = (const float4*)fT2;

    // ---- Phase A setup: thread owns position `tid` (tid < NPOS) ----
    float rAx[2], rAy[2], rAz[2], trn[2][3];
#pragma unroll
    for (int v = 0; v < 2; v++) {
        trn[v][0] = projl[v * 12 + 9];
        trn[v][1] = projl[v * 12 + 10];
        trn[v][2] = projl[v * 12 + 11];
    }
    bool aok = false;
    {
        int pp = (tid < NPOS) ? tid : 0;
        int py = pp / HALO, px = pp % HALO;
        int hyi = baseH + py, hxi = baseW + px;
        aok = (tid < NPOS) && hyi >= 0 && hyi < Hc && hxi >= 0 && hxi < Wc;
        float hx = (float)hxi, hy = (float)hyi;
#pragma unroll
        for (int v = 0; v < 2; v++) {
            const float* R = projl + v * 12;
            rAx[v] = fmaf(R[0], hx, fmaf(R[1], hy, R[2]));
            rAy[v] = fmaf(R[3], hx, fmaf(R[4], hy, R[5]));
            rAz[v] = fmaf(R[6], hx, fmaf(R[7], hy, R[8]));
        }
    }

    // ---- Phase B setup: per-pass validity + hoisted depth-independent ref gathers ----
    int    bmask = 0;
    float4 rfv[NPASS];
#pragma unroll
    for (int s = 0; s < NPASS; s++) {
        int p = g + s * 64;
        bool act = p < NPOS;
        int pp = act ? p : 0;
        int py = pp / HALO, px = pp % HALO;
        int hyi = baseH + py, hxi = baseW + px;
        bool ok = act && hyi >= 0 && hyi < Hc && hxi >= 0 && hxi < Wc;
        if (ok) bmask |= (1 << s);
        rfv[s] = ok ? fT0_4[(hyi * Wc + hxi) * 8 + e] : make_float4(0.f, 0.f, 0.f, 0.f);
    }

    float cost[DCHUNK];
#pragma unroll
    for (int i = 0; i < DCHUNK; i++) cost[i] = 0.f;

    const int convbase = (ty * HALO + tx) * VSTR4 + hf * 4;
    const int wbase = hf * 108;                   // float4 units: half*9*3*4

    // ---- Phase A: bilinear params for slice dpn -> par_l ----
    auto phaseA = [&](int dpn) {
        const float depthN = dvals[dpn];
        if (aok) {
            float cw[2][4]; unsigned int pk[4];
#pragma unroll
            for (int v = 0; v < 2; v++) {
                float X = fmaf(rAx[v], depthN, trn[v][0]);
                float Y = fmaf(rAy[v], depthN, trn[v][1]);
                float Z = fmaf(rAz[v], depthN, trn[v][2]);
                float iz = 1.f / Z;
                float gx = X * iz, gy = Y * iz;
                float x0f = floorf(gx), y0f = floorf(gy);
                float wx = gx - x0f, wy = gy - y0f;
                int x0 = (int)x0f, y0 = (int)y0f;
                bool vx0 = (x0 >= 0) & (x0 <= Wc - 1);
                bool vx1 = (x0 + 1 >= 0) & (x0 + 1 <= Wc - 1);
                bool vy0 = (y0 >= 0) & (y0 <= Hc - 1);
                bool vy1 = (y0 + 1 >= 0) & (y0 + 1 <= Hc - 1);
                int xc0 = min(max(x0, 0), Wc - 1), xc1 = min(max(x0 + 1, 0), Wc - 1);
                int yc0 = min(max(y0, 0), Hc - 1), yc1 = min(max(y0 + 1, 0), Hc - 1);
                float ax = 1.f - wx, ay = 1.f - wy;
                cw[v][0] = (vx0 && vy0) ? ax * ay : 0.f;
                cw[v][1] = (vx1 && vy0) ? wx * ay : 0.f;
                cw[v][2] = (vx0 && vy1) ? ax * wy : 0.f;
                cw[v][3] = (vx1 && vy1) ? wx * wy : 0.f;
                unsigned int i0 = (unsigned int)(yc0 * Wc + xc0);
                unsigned int i1 = (unsigned int)(yc0 * Wc + xc1);
                unsigned int i2 = (unsigned int)(yc1 * Wc + xc0);
                unsigned int i3 = (unsigned int)(yc1 * Wc + xc1);
                pk[v * 2 + 0] = i0 | (i1 << 16);
                pk[v * 2 + 1] = i2 | (i3 << 16);
            }
            par_l[tid * PSTR4 + 0] = make_float4(cw[0][0], cw[0][1], cw[0][2], cw[0][3]);
            par_l[tid * PSTR4 + 1] = make_float4(cw[1][0], cw[1][1], cw[1][2], cw[1][3]);
            par_l[tid * PSTR4 + 2] = make_float4(__uint_as_float(pk[0]), __uint_as_float(pk[1]),
                                                 __uint_as_float(pk[2]), __uint_as_float(pk[3]));
        }
    };

    const int dpFirst = (d0 == 0) ? 0 : d0 - 1;
    const int dpLast  = min(d0 + DCHUNK, Dc - 1);

    phaseA(dpFirst);
    __syncthreads();

    for (int dp = dpFirst; dp <= dpLast; dp++) {
        // ---- Phase B: gather + variance -> var_l (8-lane groups, 128B coalesced taps) ----
#pragma unroll
        for (int s = 0; s < NPASS; s++) {
            int p = g + s * 64;
            if (p >= NPOS) continue;                 // only pass 5, g>=4
            const int vaddr = p * VSTR4 + e;
            if (!((bmask >> s) & 1)) {
                var_l[vaddr] = make_float4(0.f, 0.f, 0.f, 0.f);
                continue;
            }
            float4 c0 = par_l[p * PSTR4 + 0];        // group-broadcast reads
            float4 c1 = par_l[p * PSTR4 + 1];
            float4 pkf = par_l[p * PSTR4 + 2];
            unsigned int u0 = __float_as_uint(pkf.x), u1 = __float_as_uint(pkf.y);
            unsigned int u2 = __float_as_uint(pkf.z), u3 = __float_as_uint(pkf.w);
            int i00 = u0 & 0xffff, i01 = u0 >> 16, i02 = u1 & 0xffff, i03 = u1 >> 16;
            int i10 = u2 & 0xffff, i11 = u2 >> 16, i12 = u3 & 0xffff, i13 = u3 >> 16;
            float4 rf  = rfv[s];
            float4 t00 = fT1_4[i00 * 8 + e];
            float4 t01 = fT1_4[i01 * 8 + e];
            float4 t10 = fT1_4[i02 * 8 + e];
            float4 t11 = fT1_4[i03 * 8 + e];
            float4 u00 = fT2_4[i10 * 8 + e];
            float4 u01 = fT2_4[i11 * 8 + e];
            float4 u10 = fT2_4[i12 * 8 + e];
            float4 u11 = fT2_4[i13 * 8 + e];
            v2f a1l = vfma2(vbc(c0.x), vlo(t00), vfma2(vbc(c0.y), vlo(t01),
                      vfma2(vbc(c0.z), vlo(t10), vbc(c0.w) * vlo(t11))));
            v2f a1h = vfma2(vbc(c0.x), vhi(t00), vfma2(vbc(c0.y), vhi(t01),
                      vfma2(vbc(c0.z), vhi(t10), vbc(c0.w) * vhi(t11))));
            v2f a2l = vfma2(vbc(c1.x), vlo(u00), vfma2(vbc(c1.y), vlo(u01),
                      vfma2(vbc(c1.z), vlo(u10), vbc(c1.w) * vlo(u11))));
            v2f a2h = vfma2(vbc(c1.x), vhi(u00), vfma2(vbc(c1.y), vhi(u01),
                      vfma2(vbc(c1.z), vhi(u10), vbc(c1.w) * vhi(u11))));
            v2f rl = vlo(rf), rh = vhi(rf);
            v2f sml = rl + a1l + a2l;
            v2f smh = rh + a1h + a2h;
            v2f sql = vfma2(a2l, a2l, vfma2(a1l, a1l, rl * rl));
            v2f sqh = vfma2(a2h, a2h, vfma2(a1h, a1h, rh * rh));
            v2f vrl = vfma2(sml * sml, vbc(-1.f / 9.f), sql * vbc(1.f / 3.f));
            v2f vrh = vfma2(smh * smh, vbc(-1.f / 9.f), sqh * vbc(1.f / 3.f));
            var_l[vaddr] = make_float4(vrl.x, vrl.y, vrh.x, vrh.y);
        }
        __syncthreads();

        // ---- Phase A for next slice (overlaps conv latency) ----
        if (dp < dpLast) phaseA(dp + 1);

        // ---- 3x3 spatial conv, 3 kd planes, 16 channels (this half) ----
        v2f a0v = vbc(0.f), a1v = vbc(0.f), a2v = vbc(0.f);
#pragma unroll
        for (int k = 0; k < 9; k++) {
            const int off = (k / 3) * HALO + (k % 3);
#pragma unroll
            for (int c4 = 0; c4 < 4; c4++) {
                float4 v  = var_l[convbase + off * VSTR4 + c4];
                float4 w0 = w2_4[wbase + k * 12 + 0 * 4 + c4];
                float4 w1 = w2_4[wbase + k * 12 + 1 * 4 + c4];
                float4 w2v = w2_4[wbase + k * 12 + 2 * 4 + c4];
                a0v = vfma2(vlo(v), vlo(w0), a0v); a0v = vfma2(vhi(v), vhi(w0), a0v);
                a1v = vfma2(vlo(v), vlo(w1), a1v); a1v = vfma2(vhi(v), vhi(w1), a1v);
                a2v = vfma2(vlo(v), vlo(w2v), a2v); a2v = vfma2(vhi(v), vhi(w2v), a2v);
            }
        }
        float a0 = a0v.x + a0v.y, a1 = a1v.x + a1v.y, a2 = a2v.x + a2v.y;
        // cost(d) = A0(d-1) + A1(d) + A2(d+1)
        int r;
        r = dp + 1 - d0; if (r >= 0 && r < DCHUNK) cost[r] += a0;
        r = dp - d0;     if (r >= 0 && r < DCHUNK) cost[r] += a1;
        r = dp - 1 - d0; if (r >= 0 && r < DCHUNK) cost[r] += a2;
        __syncthreads();
    }

    // ---- combine the two halves (reuse par_l as scratch) ----
    float* red = (float*)par_l;
    if (hf == 1) {
#pragma unroll
        for (int i = 0; i < DCHUNK; i++) red[tidh * DCHUNK + i] = cost[i];
    }
    __syncthreads();
    if (hf == 0) {
        const int pr = tileY * TS + ty, pc = tileX * TS + tx;
#pragma unroll
        for (int i = 0; i < DCHUNK; i++)
            costvol[(d0 + i) * HWc + pr * Wc + pc] = cost[i] + red[tidh * DCHUNK + i];
    }
}

// ---------------- kernel 3: softmax over depth + regression ----------------
__global__ void k_softmax(const float* __restrict__ costvol, const float* __restrict__ dvals,
                          const float* __restrict__ breg, float* __restrict__ out)
{
    const int px = blockIdx.x * 256 + threadIdx.x;
    if (px >= HWc) return;
    const float bias = breg[0];
    float c[Dc];
    float m = -1e30f;
#pragma unroll
    for (int d = 0; d < Dc; d++) {
        c[d] = costvol[d * HWc + px] + bias;
        m = fmaxf(m, c[d]);
    }
    float se = 0.f, sed = 0.f, me = 0.f;
#pragma unroll
    for (int d = 0; d < Dc; d++) {
        float e = __expf(c[d] - m);
        se += e;
        sed = fmaf(e, dvals[d], sed);
        me = fmaxf(me, e);
    }
    float inv = 1.f / se;
    out[px]       = sed * inv;   // depth
    out[HWc + px] = me * inv;    // photometric confidence
}

extern "C" void kernel_launch(void* const* d_in, const int* in_sizes, int n_in,
                              void* d_out, int out_size, void* d_ws, size_t ws_size,
                              hipStream_t stream) {
    const float* f0    = (const float*)d_in[0];
    const float* f1    = (const float*)d_in[1];
    const float* f2    = (const float*)d_in[2];
    const float* proj  = (const float*)d_in[3];
    const float* dvals = (const float*)d_in[4];
    const float* wreg  = (const float*)d_in[5];
    const float* breg  = (const float*)d_in[6];

    float* ws      = (float*)d_ws;
    float* wsproj  = ws;                    // 24 floats (pad to 32)
    float* w2      = ws + 32;               // 864 floats
    float* fT0     = ws + 896;              // 655360 floats each
    float* fT1     = fT0 + (size_t)HWc * Cc;
    float* fT2     = fT1 + (size_t)HWc * Cc;
    float* costvol = fT2 + (size_t)HWc * Cc;   // Dc*HWc floats

    k_pre<<<dim3((HWc + 255) / 256, 3), 256, 0, stream>>>(f0, f1, f2, proj, wreg,
                                                          fT0, fT1, fT2, wsproj, w2);

    dim3 grid(Wc / TS, Hc / TS, NCHUNK);   // 10 x 8 x 6 = 480 blocks of 512
    k_cost<<<grid, 512, 0, stream>>>(fT0, fT1, fT2, dvals, (const float4*)w2,
                                     wsproj, costvol);

    k_softmax<<<(HWc + 255) / 256, 256, 0, stream>>>(costvol, dvals, breg, (float*)d_out);
}

// Round 7
// 671.212 us; speedup vs baseline: 1.5576x; 1.5576x over previous
//
#include <hip/hip_runtime.h>
#include <math.h>

#define Cc 32
#define Hc 128
#define Wc 160
#define Dc 48
#define HWc (Hc*Wc)
#define TS 16
#define HALO (TS+2)           // 18
#define NPOS (HALO*HALO)      // 324
#define DCHUNK 8
#define NCHUNK (Dc/DCHUNK)    // 6
#define VSTR4 11              // var position stride in float4 (44 floats; 12p%32 bank walk)
#define PSTR4 3               // param stride in float4 (cw0, cw1, idx-pack)
#define NPASS 6               // ceil(NPOS / 64 groups)

typedef float v2f __attribute__((ext_vector_type(2)));
static __device__ __forceinline__ v2f vfma2(v2f a, v2f b, v2f c) { return __builtin_elementwise_fma(a, b, c); }
static __device__ __forceinline__ v2f vlo(float4 v) { v2f r; r.x = v.x; r.y = v.y; return r; }
static __device__ __forceinline__ v2f vhi(float4 v) { v2f r; r.x = v.z; r.y = v.w; return r; }
static __device__ __forceinline__ v2f vbc(float s) { v2f r; r.x = s; r.y = s; return r; }

// ---------------- kernel 1: transpose CHW->HWC + proj matrices + weight repack ----------------
__global__ void k_pre(const float* __restrict__ f0, const float* __restrict__ f1,
                      const float* __restrict__ f2, const float* __restrict__ proj,
                      const float* __restrict__ wreg,
                      float* __restrict__ o0, float* __restrict__ o1, float* __restrict__ o2,
                      float* __restrict__ wsproj, float* __restrict__ w2) {
    const int tid = threadIdx.x;
    const int p = blockIdx.x * 256 + tid;
    if (p < HWc) {
        const float* f = (blockIdx.y == 0) ? f0 : (blockIdx.y == 1) ? f1 : f2;
        float*       o = (blockIdx.y == 0) ? o0 : (blockIdx.y == 1) ? o1 : o2;
        float v[Cc];
#pragma unroll
        for (int c = 0; c < Cc; c++) v[c] = f[c * HWc + p];   // coalesced across lanes
        float4* o4 = (float4*)(o + (size_t)p * Cc);
#pragma unroll
        for (int j = 0; j < 8; j++)
            o4[j] = make_float4(v[4 * j], v[4 * j + 1], v[4 * j + 2], v[4 * j + 3]);
    }
    if (blockIdx.x == 0 && blockIdx.y == 0) {
        // weight repack: w2[half(2)][khkw(9)][kd(3)][c(16)]
        for (int i = tid; i < 2 * 9 * 3 * 16; i += 256) {
            int c = i & 15;
            int t = i >> 4;
            int kd = t % 3;
            int t2 = t / 3;
            int khkw = t2 % 9;
            int half = t2 / 9;
            int ch = half * 16 + c;
            w2[i] = wreg[ch * 27 + kd * 9 + khkw];
        }
        if (tid == 0) {
            float a[4][8];
            for (int i = 0; i < 4; i++)
                for (int j = 0; j < 4; j++) {
                    a[i][j]     = proj[i * 4 + j];
                    a[i][j + 4] = (i == j) ? 1.f : 0.f;
                }
            for (int col = 0; col < 4; col++) {
                int piv = col; float best = fabsf(a[col][col]);
                for (int r = col + 1; r < 4; r++) {
                    float v = fabsf(a[r][col]);
                    if (v > best) { best = v; piv = r; }
                }
                if (piv != col)
                    for (int j = 0; j < 8; j++) { float t = a[col][j]; a[col][j] = a[piv][j]; a[piv][j] = t; }
                float inv = 1.f / a[col][col];
                for (int j = 0; j < 8; j++) a[col][j] *= inv;
                for (int r = 0; r < 4; r++) if (r != col) {
                    float f = a[r][col];
                    for (int j = 0; j < 8; j++) a[r][j] -= f * a[col][j];
                }
            }
            for (int v = 1; v < 3; v++) {
                const float* P = proj + v * 16;
                float M[3][4];
                for (int i = 0; i < 3; i++)
                    for (int j = 0; j < 4; j++) {
                        float s = 0.f;
                        for (int k = 0; k < 4; k++) s += P[i * 4 + k] * a[k][4 + j];
                        M[i][j] = s;
                    }
                float* o = wsproj + (v - 1) * 12;
                o[0] = M[0][0]; o[1] = M[0][1]; o[2] = M[0][2];
                o[3] = M[1][0]; o[4] = M[1][1]; o[5] = M[1][2];
                o[6] = M[2][0]; o[7] = M[2][1]; o[8] = M[2][2];
                o[9] = M[0][3]; o[10] = M[1][3]; o[11] = M[2][3];
            }
        }
    }
}

// ---------------- kernel 2: fused warp + variance + 3D conv, 512-thread merged block ----------------
// Launch-bounds VGPR-cap rule (empirical): cap ~= 256 / waves_per_EU_arg.
//   (256,4)->64 spilled (R2); (512,4)->64 spilled (R6, 2.35GB traffic, 978us);
//   (256,2)->128 fine. So (512,2): cap 128. LDS 72.7KB limits to 2 blocks/CU
//   (16 waves) regardless. Spill guard: WRITE_SIZE must stay ~8MB.
__global__ __launch_bounds__(512, 2) void k_cost(
    const float* __restrict__ fT0, const float* __restrict__ fT1, const float* __restrict__ fT2,
    const float* __restrict__ dvals, const float4* __restrict__ w2_4,
    const float* __restrict__ wsproj, float* __restrict__ costvol)
{
    __shared__ float4 var_l[NPOS * VSTR4];   // 57024 B
    __shared__ float4 par_l[NPOS * PSTR4];   // 15552 B
    __shared__ float projl[24];

    const int tid = threadIdx.x;
    if (tid < 24) projl[tid] = wsproj[tid];
    __syncthreads();

    const int tileX = blockIdx.x;                 // 0..9
    const int tileY = blockIdx.y;                 // 0..7
    const int d0    = blockIdx.z * DCHUNK;
    const int tidh = tid & 255;                   // pixel id within tile
    const int hf   = tid >> 8;                    // channel half (0/1)
    const int tx = tidh & 15, ty = tidh >> 4;
    const int baseH = tileY * TS - 1, baseW = tileX * TS - 1;

    const int g = tid >> 3;                       // gather group (0..63)
    const int e = tid & 7;                        // float4 slot within 32-ch record

    const float4* fT0_4 = (const float4*)fT0;
    const float4* fT1_4 = (const float4*)fT1;
    const float4* fT2_4 = (const float4*)fT2;

    // ---- Phase A setup: thread owns position `tid` (tid < NPOS) ----
    float rAx[2], rAy[2], rAz[2], trn[2][3];
#pragma unroll
    for (int v = 0; v < 2; v++) {
        trn[v][0] = projl[v * 12 + 9];
        trn[v][1] = projl[v * 12 + 10];
        trn[v][2] = projl[v * 12 + 11];
    }
    bool aok = false;
    {
        int pp = (tid < NPOS) ? tid : 0;
        int py = pp / HALO, px = pp % HALO;
        int hyi = baseH + py, hxi = baseW + px;
        aok = (tid < NPOS) && hyi >= 0 && hyi < Hc && hxi >= 0 && hxi < Wc;
        float hx = (float)hxi, hy = (float)hyi;
#pragma unroll
        for (int v = 0; v < 2; v++) {
            const float* R = projl + v * 12;
            rAx[v] = fmaf(R[0], hx, fmaf(R[1], hy, R[2]));
            rAy[v] = fmaf(R[3], hx, fmaf(R[4], hy, R[5]));
            rAz[v] = fmaf(R[6], hx, fmaf(R[7], hy, R[8]));
        }
    }

    // ---- Phase B setup: per-pass validity + hoisted depth-independent ref gathers ----
    int    bmask = 0;
    float4 rfv[NPASS];
#pragma unroll
    for (int s = 0; s < NPASS; s++) {
        int p = g + s * 64;
        bool act = p < NPOS;
        int pp = act ? p : 0;
        int py = pp / HALO, px = pp % HALO;
        int hyi = baseH + py, hxi = baseW + px;
        bool ok = act && hyi >= 0 && hyi < Hc && hxi >= 0 && hxi < Wc;
        if (ok) bmask |= (1 << s);
        rfv[s] = ok ? fT0_4[(hyi * Wc + hxi) * 8 + e] : make_float4(0.f, 0.f, 0.f, 0.f);
    }

    float cost[DCHUNK];
#pragma unroll
    for (int i = 0; i < DCHUNK; i++) cost[i] = 0.f;

    const int convbase = (ty * HALO + tx) * VSTR4 + hf * 4;
    const int wbase = hf * 108;                   // float4 units: half*9*3*4

    // ---- Phase A: bilinear params for slice dpn -> par_l ----
    auto phaseA = [&](int dpn) {
        const float depthN = dvals[dpn];
        if (aok) {
            float cw[2][4]; unsigned int pk[4];
#pragma unroll
            for (int v = 0; v < 2; v++) {
                float X = fmaf(rAx[v], depthN, trn[v][0]);
                float Y = fmaf(rAy[v], depthN, trn[v][1]);
                float Z = fmaf(rAz[v], depthN, trn[v][2]);
                float iz = 1.f / Z;
                float gx = X * iz, gy = Y * iz;
                float x0f = floorf(gx), y0f = floorf(gy);
                float wx = gx - x0f, wy = gy - y0f;
                int x0 = (int)x0f, y0 = (int)y0f;
                bool vx0 = (x0 >= 0) & (x0 <= Wc - 1);
                bool vx1 = (x0 + 1 >= 0) & (x0 + 1 <= Wc - 1);
                bool vy0 = (y0 >= 0) & (y0 <= Hc - 1);
                bool vy1 = (y0 + 1 >= 0) & (y0 + 1 <= Hc - 1);
                int xc0 = min(max(x0, 0), Wc - 1), xc1 = min(max(x0 + 1, 0), Wc - 1);
                int yc0 = min(max(y0, 0), Hc - 1), yc1 = min(max(y0 + 1, 0), Hc - 1);
                float ax = 1.f - wx, ay = 1.f - wy;
                cw[v][0] = (vx0 && vy0) ? ax * ay : 0.f;
                cw[v][1] = (vx1 && vy0) ? wx * ay : 0.f;
                cw[v][2] = (vx0 && vy1) ? ax * wy : 0.f;
                cw[v][3] = (vx1 && vy1) ? wx * wy : 0.f;
                unsigned int i0 = (unsigned int)(yc0 * Wc + xc0);
                unsigned int i1 = (unsigned int)(yc0 * Wc + xc1);
                unsigned int i2 = (unsigned int)(yc1 * Wc + xc0);
                unsigned int i3 = (unsigned int)(yc1 * Wc + xc1);
                pk[v * 2 + 0] = i0 | (i1 << 16);
                pk[v * 2 + 1] = i2 | (i3 << 16);
            }
            par_l[tid * PSTR4 + 0] = make_float4(cw[0][0], cw[0][1], cw[0][2], cw[0][3]);
            par_l[tid * PSTR4 + 1] = make_float4(cw[1][0], cw[1][1], cw[1][2], cw[1][3]);
            par_l[tid * PSTR4 + 2] = make_float4(__uint_as_float(pk[0]), __uint_as_float(pk[1]),
                                                 __uint_as_float(pk[2]), __uint_as_float(pk[3]));
        }
    };

    const int dpFirst = (d0 == 0) ? 0 : d0 - 1;
    const int dpLast  = min(d0 + DCHUNK, Dc - 1);

    phaseA(dpFirst);
    __syncthreads();

    for (int dp = dpFirst; dp <= dpLast; dp++) {
        // ---- Phase B: gather + variance -> var_l (8-lane groups, 128B coalesced taps) ----
#pragma unroll
        for (int s = 0; s < NPASS; s++) {
            int p = g + s * 64;
            if (p >= NPOS) continue;                 // only pass 5, g>=4
            const int vaddr = p * VSTR4 + e;
            if (!((bmask >> s) & 1)) {
                var_l[vaddr] = make_float4(0.f, 0.f, 0.f, 0.f);
                continue;
            }
            float4 c0 = par_l[p * PSTR4 + 0];        // group-broadcast reads
            float4 c1 = par_l[p * PSTR4 + 1];
            float4 pkf = par_l[p * PSTR4 + 2];
            unsigned int u0 = __float_as_uint(pkf.x), u1 = __float_as_uint(pkf.y);
            unsigned int u2 = __float_as_uint(pkf.z), u3 = __float_as_uint(pkf.w);
            int i00 = u0 & 0xffff, i01 = u0 >> 16, i02 = u1 & 0xffff, i03 = u1 >> 16;
            int i10 = u2 & 0xffff, i11 = u2 >> 16, i12 = u3 & 0xffff, i13 = u3 >> 16;
            float4 rf  = rfv[s];
            float4 t00 = fT1_4[i00 * 8 + e];
            float4 t01 = fT1_4[i01 * 8 + e];
            float4 t10 = fT1_4[i02 * 8 + e];
            float4 t11 = fT1_4[i03 * 8 + e];
            float4 u00 = fT2_4[i10 * 8 + e];
            float4 u01 = fT2_4[i11 * 8 + e];
            float4 u10 = fT2_4[i12 * 8 + e];
            float4 u11 = fT2_4[i13 * 8 + e];
            v2f a1l = vfma2(vbc(c0.x), vlo(t00), vfma2(vbc(c0.y), vlo(t01),
                      vfma2(vbc(c0.z), vlo(t10), vbc(c0.w) * vlo(t11))));
            v2f a1h = vfma2(vbc(c0.x), vhi(t00), vfma2(vbc(c0.y), vhi(t01),
                      vfma2(vbc(c0.z), vhi(t10), vbc(c0.w) * vhi(t11))));
            v2f a2l = vfma2(vbc(c1.x), vlo(u00), vfma2(vbc(c1.y), vlo(u01),
                      vfma2(vbc(c1.z), vlo(u10), vbc(c1.w) * vlo(u11))));
            v2f a2h = vfma2(vbc(c1.x), vhi(u00), vfma2(vbc(c1.y), vhi(u01),
                      vfma2(vbc(c1.z), vhi(u10), vbc(c1.w) * vhi(u11))));
            v2f rl = vlo(rf), rh = vhi(rf);
            v2f sml = rl + a1l + a2l;
            v2f smh = rh + a1h + a2h;
            v2f sql = vfma2(a2l, a2l, vfma2(a1l, a1l, rl * rl));
            v2f sqh = vfma2(a2h, a2h, vfma2(a1h, a1h, rh * rh));
            v2f vrl = vfma2(sml * sml, vbc(-1.f / 9.f), sql * vbc(1.f / 3.f));
            v2f vrh = vfma2(smh * smh, vbc(-1.f / 9.f), sqh * vbc(1.f / 3.f));
            var_l[vaddr] = make_float4(vrl.x, vrl.y, vrh.x, vrh.y);
        }
        __syncthreads();

        // ---- Phase A for next slice (overlaps conv latency) ----
        if (dp < dpLast) phaseA(dp + 1);

        // ---- 3x3 spatial conv, 3 kd planes, 16 channels (this half) ----
        v2f a0v = vbc(0.f), a1v = vbc(0.f), a2v = vbc(0.f);
#pragma unroll
        for (int k = 0; k < 9; k++) {
            const int off = (k / 3) * HALO + (k % 3);
#pragma unroll
            for (int c4 = 0; c4 < 4; c4++) {
                float4 v  = var_l[convbase + off * VSTR4 + c4];
                float4 w0 = w2_4[wbase + k * 12 + 0 * 4 + c4];
                float4 w1 = w2_4[wbase + k * 12 + 1 * 4 + c4];
                float4 w2v = w2_4[wbase + k * 12 + 2 * 4 + c4];
                a0v = vfma2(vlo(v), vlo(w0), a0v); a0v = vfma2(vhi(v), vhi(w0), a0v);
                a1v = vfma2(vlo(v), vlo(w1), a1v); a1v = vfma2(vhi(v), vhi(w1), a1v);
                a2v = vfma2(vlo(v), vlo(w2v), a2v); a2v = vfma2(vhi(v), vhi(w2v), a2v);
            }
        }
        float a0 = a0v.x + a0v.y, a1 = a1v.x + a1v.y, a2 = a2v.x + a2v.y;
        // cost(d) = A0(d-1) + A1(d) + A2(d+1)
        int r;
        r = dp + 1 - d0; if (r >= 0 && r < DCHUNK) cost[r] += a0;
        r = dp - d0;     if (r >= 0 && r < DCHUNK) cost[r] += a1;
        r = dp - 1 - d0; if (r >= 0 && r < DCHUNK) cost[r] += a2;
        __syncthreads();
    }

    // ---- combine the two halves (reuse par_l as scratch) ----
    float* red = (float*)par_l;
    if (hf == 1) {
#pragma unroll
        for (int i = 0; i < DCHUNK; i++) red[tidh * DCHUNK + i] = cost[i];
    }
    __syncthreads();
    if (hf == 0) {
        const int pr = tileY * TS + ty, pc = tileX * TS + tx;
#pragma unroll
        for (int i = 0; i < DCHUNK; i++)
            costvol[(d0 + i) * HWc + pr * Wc + pc] = cost[i] + red[tidh * DCHUNK + i];
    }
}

// ---------------- kernel 3: softmax over depth + regression ----------------
__global__ void k_softmax(const float* __restrict__ costvol, const float* __restrict__ dvals,
                          const float* __restrict__ breg, float* __restrict__ out)
{
    const int px = blockIdx.x * 256 + threadIdx.x;
    if (px >= HWc) return;
    const float bias = breg[0];
    float c[Dc];
    float m = -1e30f;
#pragma unroll
    for (int d = 0; d < Dc; d++) {
        c[d] = costvol[d * HWc + px] + bias;
        m = fmaxf(m, c[d]);
    }
    float se = 0.f, sed = 0.f, me = 0.f;
#pragma unroll
    for (int d = 0; d < Dc; d++) {
        float e = __expf(c[d] - m);
        se += e;
        sed = fmaf(e, dvals[d], sed);
        me = fmaxf(me, e);
    }
    float inv = 1.f / se;
    out[px]       = sed * inv;   // depth
    out[HWc + px] = me * inv;    // photometric confidence
}

extern "C" void kernel_launch(void* const* d_in, const int* in_sizes, int n_in,
                              void* d_out, int out_size, void* d_ws, size_t ws_size,
                              hipStream_t stream) {
    const float* f0    = (const float*)d_in[0];
    const float* f1    = (const float*)d_in[1];
    const float* f2    = (const float*)d_in[2];
    const float* proj  = (const float*)d_in[3];
    const float* dvals = (const float*)d_in[4];
    const float* wreg  = (const float*)d_in[5];
    const float* breg  = (const float*)d_in[6];

    float* ws      = (float*)d_ws;
    float* wsproj  = ws;                    // 24 floats (pad to 32)
    float* w2      = ws + 32;               // 864 floats
    float* fT0     = ws + 896;              // 655360 floats each
    float* fT1     = fT0 + (size_t)HWc * Cc;
    float* fT2     = fT1 + (size_t)HWc * Cc;
    float* costvol = fT2 + (size_t)HWc * Cc;   // Dc*HWc floats

    k_pre<<<dim3((HWc + 255) / 256, 3), 256, 0, stream>>>(f0, f1, f2, proj, wreg,
                                                          fT0, fT1, fT2, wsproj, w2);

    dim3 grid(Wc / TS, Hc / TS, NCHUNK);   // 10 x 8 x 6 = 480 blocks of 512
    k_cost<<<grid, 512, 0, stream>>>(fT0, fT1, fT2, dvals, (const float4*)w2,
                                     wsproj, costvol);

    k_softmax<<<(HWc + 255) / 256, 256, 0, stream>>>(costvol, dvals, breg, (float*)d_out);
}

// Round 8
// 215.419 us; speedup vs baseline: 4.8533x; 3.1158x over previous
//
#include <hip/hip_runtime.h>
#include <hip/hip_fp16.h>
#include <math.h>

#define Cc 32
#define CH 16                 // channels per half-block
#define Hc 128
#define Wc 160
#define Dc 48
#define HWc (Hc*Wc)
#define TS 16
#define HALO (TS+2)           // 18
#define NPOS (HALO*HALO)      // 324
#define DCHUNK 8
#define NCHUNK (Dc/DCHUNK)    // 6
#define VSTR4 5               // var position stride in float4 (20 floats)
#define PSTR4 2               // param stride in float4 (fp16 cw-pack, idx-pack)
#define NPASS 6               // ceil(NPOS / 64 quads)

typedef float v2f __attribute__((ext_vector_type(2)));
static __device__ __forceinline__ v2f vfma2(v2f a, v2f b, v2f c) { return __builtin_elementwise_fma(a, b, c); }
static __device__ __forceinline__ v2f vlo(float4 v) { v2f r; r.x = v.x; r.y = v.y; return r; }
static __device__ __forceinline__ v2f vhi(float4 v) { v2f r; r.x = v.z; r.y = v.w; return r; }
static __device__ __forceinline__ v2f vbc(float s) { v2f r; r.x = s; r.y = s; return r; }

union PackCW { __half2 h[4]; float4 f; };

// ---------------- kernel 1: transpose CHW->HWC + proj matrices + weight repack ----------------
__global__ void k_pre(const float* __restrict__ f0, const float* __restrict__ f1,
                      const float* __restrict__ f2, const float* __restrict__ proj,
                      const float* __restrict__ wreg,
                      float* __restrict__ o0, float* __restrict__ o1, float* __restrict__ o2,
                      float* __restrict__ wsproj, float* __restrict__ w2) {
    const int tid = threadIdx.x;
    const int p = blockIdx.x * 256 + tid;
    if (p < HWc) {
        const float* f = (blockIdx.y == 0) ? f0 : (blockIdx.y == 1) ? f1 : f2;
        float*       o = (blockIdx.y == 0) ? o0 : (blockIdx.y == 1) ? o1 : o2;
        float v[Cc];
#pragma unroll
        for (int c = 0; c < Cc; c++) v[c] = f[c * HWc + p];   // coalesced across lanes
        float4* o4 = (float4*)(o + (size_t)p * Cc);
#pragma unroll
        for (int j = 0; j < 8; j++)
            o4[j] = make_float4(v[4 * j], v[4 * j + 1], v[4 * j + 2], v[4 * j + 3]);
    }
    if (blockIdx.x == 0 && blockIdx.y == 0) {
        // weight repack: w2[half(2)][khkw(9)][kd(3)][c(16)]
        for (int i = tid; i < 2 * 9 * 3 * CH; i += 256) {
            int c = i & 15;
            int t = i >> 4;
            int kd = t % 3;
            int t2 = t / 3;
            int khkw = t2 % 9;
            int half = t2 / 9;
            int ch = half * CH + c;
            w2[i] = wreg[ch * 27 + kd * 9 + khkw];
        }
        if (tid == 0) {
            float a[4][8];
            for (int i = 0; i < 4; i++)
                for (int j = 0; j < 4; j++) {
                    a[i][j]     = proj[i * 4 + j];
                    a[i][j + 4] = (i == j) ? 1.f : 0.f;
                }
            for (int col = 0; col < 4; col++) {
                int piv = col; float best = fabsf(a[col][col]);
                for (int r = col + 1; r < 4; r++) {
                    float v = fabsf(a[r][col]);
                    if (v > best) { best = v; piv = r; }
                }
                if (piv != col)
                    for (int j = 0; j < 8; j++) { float t = a[col][j]; a[col][j] = a[piv][j]; a[piv][j] = t; }
                float inv = 1.f / a[col][col];
                for (int j = 0; j < 8; j++) a[col][j] *= inv;
                for (int r = 0; r < 4; r++) if (r != col) {
                    float f = a[r][col];
                    for (int j = 0; j < 8; j++) a[r][j] -= f * a[col][j];
                }
            }
            for (int v = 1; v < 3; v++) {
                const float* P = proj + v * 16;
                float M[3][4];
                for (int i = 0; i < 3; i++)
                    for (int j = 0; j < 4; j++) {
                        float s = 0.f;
                        for (int k = 0; k < 4; k++) s += P[i * 4 + k] * a[k][4 + j];
                        M[i][j] = s;
                    }
                float* o = wsproj + (v - 1) * 12;
                o[0] = M[0][0]; o[1] = M[0][1]; o[2] = M[0][2];
                o[3] = M[1][0]; o[4] = M[1][1]; o[5] = M[1][2];
                o[6] = M[2][0]; o[7] = M[2][1]; o[8] = M[2][2];
                o[9] = M[0][3]; o[10] = M[1][3]; o[11] = M[2][3];
            }
        }
    }
}

// ---------------- kernel 2: fused warp + variance + 3D conv (per channel half) ----------------
// 256 threads, launch_bounds(256,2) -> 128-VGPR cap (the only non-spilling config:
// R2 (256,4)=64 spilled; R6 (512,4)=64 spilled; R7 (512,2)=128 still spilled at 512thr).
// R8: R5 producer/consumer base + v2f packed math + ref-tap hoist (rfv[6]) +
// fp16-packed bilinear weights (par_l 15.5->10.4KB) so LDS=36.4KB -> 4 blocks/CU
// -> 1024 slots >= 960 grid = single generation. Spill guard: WRITE_SIZE ~7.7MB.
__global__ __launch_bounds__(256, 2) void k_cost(
    const float* __restrict__ fT0, const float* __restrict__ fT1, const float* __restrict__ fT2,
    const float* __restrict__ dvals, const float4* __restrict__ w2_4,
    const float* __restrict__ wsproj, float* __restrict__ costA, float* __restrict__ costB)
{
    __shared__ float4 var_l[NPOS * VSTR4];   // 25920 B
    __shared__ float4 par_l[NPOS * PSTR4];   // 10368 B
    __shared__ float projl[24];

    const int tid = threadIdx.x;
    if (tid < 24) projl[tid] = wsproj[tid];
    __syncthreads();

    const int tileX = blockIdx.x;                 // 0..9
    const int tileY = blockIdx.y;                 // 0..7
    const int hf    = blockIdx.z & 1;             // channel half
    const int d0    = (blockIdx.z >> 1) * DCHUNK;
    const int tx = tid & 15, ty = tid >> 4;
    const int baseH = tileY * TS - 1, baseW = tileX * TS - 1;

    const int posq = tid >> 2;                    // quad id (0..63): position within pass
    const int cc   = tid & 3;                     // float4 slot within half-record
    const int co   = hf * 4 + cc;                 // float4 offset into 32-ch record

    const float4* fT0_4 = (const float4*)fT0;
    const float4* fT1_4 = (const float4*)fT1;
    const float4* fT2_4 = (const float4*)fT2;

    // ---- Phase A setup: thread owns positions tid, tid+256; rays hoisted ----
    float rAx[2][2], rAy[2][2], rAz[2][2];
    float trn[2][3];
#pragma unroll
    for (int v = 0; v < 2; v++) {
        trn[v][0] = projl[v * 12 + 9];
        trn[v][1] = projl[v * 12 + 10];
        trn[v][2] = projl[v * 12 + 11];
    }
    int amask = 0;
#pragma unroll
    for (int s = 0; s < 2; s++) {
        int p = tid + s * 256;
        bool act = p < NPOS;
        int pp = act ? p : 0;
        int py = pp / HALO, px = pp % HALO;
        int hyi = baseH + py, hxi = baseW + px;
        bool ok = act && hyi >= 0 && hyi < Hc && hxi >= 0 && hxi < Wc;
        if (ok) amask |= (1 << s);
        float hx = (float)hxi, hy = (float)hyi;
#pragma unroll
        for (int v = 0; v < 2; v++) {
            const float* R = projl + v * 12;
            rAx[s][v] = fmaf(R[0], hx, fmaf(R[1], hy, R[2]));
            rAy[s][v] = fmaf(R[3], hx, fmaf(R[4], hy, R[5]));
            rAz[s][v] = fmaf(R[6], hx, fmaf(R[7], hy, R[8]));
        }
    }

    // ---- Phase B setup: per-pass validity + hoisted depth-independent ref taps ----
    int    bmask = 0;
    float4 rfv[NPASS];
#pragma unroll
    for (int s = 0; s < NPASS; s++) {
        int p = posq + s * 64;
        bool act = p < NPOS;
        int pp = act ? p : 0;
        int py = pp / HALO, px = pp % HALO;
        int hyi = baseH + py, hxi = baseW + px;
        bool ok = act && hyi >= 0 && hyi < Hc && hxi >= 0 && hxi < Wc;
        if (ok) bmask |= (1 << s);
        rfv[s] = ok ? fT0_4[(hyi * Wc + hxi) * 8 + co] : make_float4(0.f, 0.f, 0.f, 0.f);
    }

    float cost[DCHUNK];
#pragma unroll
    for (int i = 0; i < DCHUNK; i++) cost[i] = 0.f;

    const int convbase = (ty * HALO + tx) * VSTR4;   // float4 index of (ty,tx)
    const int wbase = hf * 108;                      // float4 units: half*9*3*4

    // ---- Phase A: bilinear params for slice dpn -> par_l (fp16 cw + u16 idx) ----
    auto phaseA = [&](int dpn) {
        const float depthN = dvals[dpn];
#pragma unroll
        for (int s = 0; s < 2; s++) {
            int p = tid + s * 256;
            if (p >= NPOS) break;
            if (!((amask >> s) & 1)) continue;
            float cw[2][4]; unsigned int pk[4];
#pragma unroll
            for (int v = 0; v < 2; v++) {
                float X = fmaf(rAx[s][v], depthN, trn[v][0]);
                float Y = fmaf(rAy[s][v], depthN, trn[v][1]);
                float Z = fmaf(rAz[s][v], depthN, trn[v][2]);
                float iz = 1.f / Z;
                float gx = X * iz, gy = Y * iz;
                float x0f = floorf(gx), y0f = floorf(gy);
                float wx = gx - x0f, wy = gy - y0f;
                int x0 = (int)x0f, y0 = (int)y0f;
                bool vx0 = (x0 >= 0) & (x0 <= Wc - 1);
                bool vx1 = (x0 + 1 >= 0) & (x0 + 1 <= Wc - 1);
                bool vy0 = (y0 >= 0) & (y0 <= Hc - 1);
                bool vy1 = (y0 + 1 >= 0) & (y0 + 1 <= Hc - 1);
                int xc0 = min(max(x0, 0), Wc - 1), xc1 = min(max(x0 + 1, 0), Wc - 1);
                int yc0 = min(max(y0, 0), Hc - 1), yc1 = min(max(y0 + 1, 0), Hc - 1);
                float ax = 1.f - wx, ay = 1.f - wy;
                cw[v][0] = (vx0 && vy0) ? ax * ay : 0.f;
                cw[v][1] = (vx1 && vy0) ? wx * ay : 0.f;
                cw[v][2] = (vx0 && vy1) ? ax * wy : 0.f;
                cw[v][3] = (vx1 && vy1) ? wx * wy : 0.f;
                unsigned int i0 = (unsigned int)(yc0 * Wc + xc0);
                unsigned int i1 = (unsigned int)(yc0 * Wc + xc1);
                unsigned int i2 = (unsigned int)(yc1 * Wc + xc0);
                unsigned int i3 = (unsigned int)(yc1 * Wc + xc1);
                pk[v * 2 + 0] = i0 | (i1 << 16);
                pk[v * 2 + 1] = i2 | (i3 << 16);
            }
            PackCW pc;
            pc.h[0] = __floats2half2_rn(cw[0][0], cw[0][1]);
            pc.h[1] = __floats2half2_rn(cw[0][2], cw[0][3]);
            pc.h[2] = __floats2half2_rn(cw[1][0], cw[1][1]);
            pc.h[3] = __floats2half2_rn(cw[1][2], cw[1][3]);
            par_l[p * PSTR4 + 0] = pc.f;
            par_l[p * PSTR4 + 1] = make_float4(__uint_as_float(pk[0]), __uint_as_float(pk[1]),
                                               __uint_as_float(pk[2]), __uint_as_float(pk[3]));
        }
    };

    const int dpFirst = (d0 == 0) ? 0 : d0 - 1;
    const int dpLast  = min(d0 + DCHUNK, Dc - 1);

    phaseA(dpFirst);
    __syncthreads();

    for (int dp = dpFirst; dp <= dpLast; dp++) {
        // ---- Phase B: gather + variance -> var_l (quad-coalesced 64B taps) ----
#pragma unroll
        for (int s = 0; s < NPASS; s++) {
            int p = posq + s * 64;
            if (p >= NPOS) continue;                 // only pass 5, posq>=4
            const int vaddr = p * VSTR4 + cc;
            if (!((bmask >> s) & 1)) {
                var_l[vaddr] = make_float4(0.f, 0.f, 0.f, 0.f);
                continue;
            }
            PackCW pc; pc.f = par_l[p * PSTR4 + 0];  // quad-broadcast reads
            float4 pkf = par_l[p * PSTR4 + 1];
            float2 c00 = __half22float2(pc.h[0]);    // cw0[0], cw0[1]
            float2 c01 = __half22float2(pc.h[1]);    // cw0[2], cw0[3]
            float2 c10 = __half22float2(pc.h[2]);    // cw1[0], cw1[1]
            float2 c11 = __half22float2(pc.h[3]);    // cw1[2], cw1[3]
            unsigned int u0 = __float_as_uint(pkf.x), u1 = __float_as_uint(pkf.y);
            unsigned int u2 = __float_as_uint(pkf.z), u3 = __float_as_uint(pkf.w);
            int i00 = u0 & 0xffff, i01 = u0 >> 16, i02 = u1 & 0xffff, i03 = u1 >> 16;
            int i10 = u2 & 0xffff, i11 = u2 >> 16, i12 = u3 & 0xffff, i13 = u3 >> 16;
            float4 rf  = rfv[s];
            float4 t00 = fT1_4[i00 * 8 + co];
            float4 t01 = fT1_4[i01 * 8 + co];
            float4 t10 = fT1_4[i02 * 8 + co];
            float4 t11 = fT1_4[i03 * 8 + co];
            float4 u00 = fT2_4[i10 * 8 + co];
            float4 u01 = fT2_4[i11 * 8 + co];
            float4 u10 = fT2_4[i12 * 8 + co];
            float4 u11 = fT2_4[i13 * 8 + co];
            v2f a1l = vfma2(vbc(c00.x), vlo(t00), vfma2(vbc(c00.y), vlo(t01),
                      vfma2(vbc(c01.x), vlo(t10), vbc(c01.y) * vlo(t11))));
            v2f a1h = vfma2(vbc(c00.x), vhi(t00), vfma2(vbc(c00.y), vhi(t01),
                      vfma2(vbc(c01.x), vhi(t10), vbc(c01.y) * vhi(t11))));
            v2f a2l = vfma2(vbc(c10.x), vlo(u00), vfma2(vbc(c10.y), vlo(u01),
                      vfma2(vbc(c11.x), vlo(u10), vbc(c11.y) * vlo(u11))));
            v2f a2h = vfma2(vbc(c10.x), vhi(u00), vfma2(vbc(c10.y), vhi(u01),
                      vfma2(vbc(c11.x), vhi(u10), vbc(c11.y) * vhi(u11))));
            v2f rl = vlo(rf), rh = vhi(rf);
            v2f sml = rl + a1l + a2l;
            v2f smh = rh + a1h + a2h;
            v2f sql = vfma2(a2l, a2l, vfma2(a1l, a1l, rl * rl));
            v2f sqh = vfma2(a2h, a2h, vfma2(a1h, a1h, rh * rh));
            v2f vrl = vfma2(sml * sml, vbc(-1.f / 9.f), sql * vbc(1.f / 3.f));
            v2f vrh = vfma2(smh * smh, vbc(-1.f / 9.f), sqh * vbc(1.f / 3.f));
            var_l[vaddr] = make_float4(vrl.x, vrl.y, vrh.x, vrh.y);
        }
        __syncthreads();

        // ---- Phase A for next slice (overlaps conv latency) ----
        if (dp < dpLast) phaseA(dp + 1);

        // ---- 3x3 spatial conv, 3 kd planes, 16 channels (this half), v2f packed ----
        v2f a0v = vbc(0.f), a1v = vbc(0.f), a2v = vbc(0.f);
#pragma unroll
        for (int k = 0; k < 9; k++) {
            const int off = (k / 3) * HALO + (k % 3);
#pragma unroll
            for (int c4 = 0; c4 < 4; c4++) {
                float4 v  = var_l[convbase + off * VSTR4 + c4];
                float4 w0 = w2_4[wbase + k * 12 + 0 * 4 + c4];
                float4 w1 = w2_4[wbase + k * 12 + 1 * 4 + c4];
                float4 w2v = w2_4[wbase + k * 12 + 2 * 4 + c4];
                a0v = vfma2(vlo(v), vlo(w0), a0v); a0v = vfma2(vhi(v), vhi(w0), a0v);
                a1v = vfma2(vlo(v), vlo(w1), a1v); a1v = vfma2(vhi(v), vhi(w1), a1v);
                a2v = vfma2(vlo(v), vlo(w2v), a2v); a2v = vfma2(vhi(v), vhi(w2v), a2v);
            }
        }
        float a0 = a0v.x + a0v.y, a1 = a1v.x + a1v.y, a2 = a2v.x + a2v.y;
        // cost(d) = A0(d-1) + A1(d) + A2(d+1)
        int r;
        r = dp + 1 - d0; if (r >= 0 && r < DCHUNK) cost[r] += a0;
        r = dp - d0;     if (r >= 0 && r < DCHUNK) cost[r] += a1;
        r = dp - 1 - d0; if (r >= 0 && r < DCHUNK) cost[r] += a2;
        __syncthreads();
    }

    float* outv = hf ? costB : costA;
    const int h = tileY * TS + ty, w = tileX * TS + tx;
#pragma unroll
    for (int i = 0; i < DCHUNK; i++)
        outv[(d0 + i) * HWc + h * Wc + w] = cost[i];
}

// ---------------- kernel 3: softmax over depth + regression ----------------
__global__ void k_softmax(const float* __restrict__ costA, const float* __restrict__ costB,
                          const float* __restrict__ dvals, const float* __restrict__ breg,
                          float* __restrict__ out)
{
    const int px = blockIdx.x * 256 + threadIdx.x;
    if (px >= HWc) return;
    const float bias = breg[0];
    float c[Dc];
    float m = -1e30f;
#pragma unroll
    for (int d = 0; d < Dc; d++) {
        c[d] = costA[d * HWc + px] + costB[d * HWc + px] + bias;
        m = fmaxf(m, c[d]);
    }
    float se = 0.f, sed = 0.f, me = 0.f;
#pragma unroll
    for (int d = 0; d < Dc; d++) {
        float e = __expf(c[d] - m);
        se += e;
        sed = fmaf(e, dvals[d], sed);
        me = fmaxf(me, e);
    }
    float inv = 1.f / se;
    out[px]       = sed * inv;   // depth
    out[HWc + px] = me * inv;    // photometric confidence
}

extern "C" void kernel_launch(void* const* d_in, const int* in_sizes, int n_in,
                              void* d_out, int out_size, void* d_ws, size_t ws_size,
                              hipStream_t stream) {
    const float* f0    = (const float*)d_in[0];
    const float* f1    = (const float*)d_in[1];
    const float* f2    = (const float*)d_in[2];
    const float* proj  = (const float*)d_in[3];
    const float* dvals = (const float*)d_in[4];
    const float* wreg  = (const float*)d_in[5];
    const float* breg  = (const float*)d_in[6];

    float* ws      = (float*)d_ws;
    float* wsproj  = ws;                    // 24 floats (pad to 32)
    float* w2      = ws + 32;               // 864 floats
    float* fT0     = ws + 896;              // 655360 floats each
    float* fT1     = fT0 + (size_t)HWc * Cc;
    float* fT2     = fT1 + (size_t)HWc * Cc;
    float* costA   = fT2 + (size_t)HWc * Cc;   // Dc*HWc floats
    float* costB   = costA + (size_t)Dc * HWc;

    k_pre<<<dim3((HWc + 255) / 256, 3), 256, 0, stream>>>(f0, f1, f2, proj, wreg,
                                                          fT0, fT1, fT2, wsproj, w2);

    dim3 grid(Wc / TS, Hc / TS, NCHUNK * 2);   // 10 x 8 x 12 = 960 blocks of 256
    k_cost<<<grid, 256, 0, stream>>>(fT0, fT1, fT2, dvals, (const float4*)w2,
                                     wsproj, costA, costB);

    k_softmax<<<(HWc + 255) / 256, 256, 0, stream>>>(costA, costB, dvals, breg, (float*)d_out);
}

// Round 9
// 203.369 us; speedup vs baseline: 5.1409x; 1.0593x over previous
//
#include <hip/hip_runtime.h>
#include <hip/hip_fp16.h>
#include <math.h>

#define Cc 32
#define CH 16                 // channels per half-block
#define Hc 128
#define Wc 160
#define Dc 48
#define HWc (Hc*Wc)
#define TS 16
#define HALO (TS+2)           // 18
#define NPOS (HALO*HALO)      // 324
#define DCHUNK 4
#define NCHUNK (Dc/DCHUNK)    // 12
#define VSTRB 48              // var position stride bytes (32B fp16 payload + 16 pad; 16-aligned)
#define PSTR4 2               // param stride in float4 (fp16 cw-pack, idx-pack)
#define NPASS 6               // ceil(NPOS / 64 quads)

typedef float v2f __attribute__((ext_vector_type(2)));
typedef _Float16 h2 __attribute__((ext_vector_type(2)));
static __device__ __forceinline__ v2f vfma2(v2f a, v2f b, v2f c) { return __builtin_elementwise_fma(a, b, c); }
static __device__ __forceinline__ v2f vlo(float4 v) { v2f r; r.x = v.x; r.y = v.y; return r; }
static __device__ __forceinline__ v2f vhi(float4 v) { v2f r; r.x = v.z; r.y = v.w; return r; }
static __device__ __forceinline__ v2f vbc(float s) { v2f r; r.x = s; r.y = s; return r; }

static __device__ __forceinline__ float hdot2(h2 a, h2 b, float acc) {
#if __has_builtin(__builtin_amdgcn_fdot2)
    return __builtin_amdgcn_fdot2(a, b, acc, false);
#else
    v2f af = __builtin_convertvector(a, v2f), bf = __builtin_convertvector(b, v2f);
    return fmaf(af.y, bf.y, fmaf(af.x, bf.x, acc));
#endif
}

union PackCW { __half2 h[4]; float4 f; };
union F4H { float4 f; h2 h[4]; };
union H2F { h2 h[2]; float2 f; };

// ---------------- kernel 1: transpose CHW->HWC + proj matrices + fp16 weight repack ----------------
__global__ void k_pre(const float* __restrict__ f0, const float* __restrict__ f1,
                      const float* __restrict__ f2, const float* __restrict__ proj,
                      const float* __restrict__ wreg,
                      float* __restrict__ o0, float* __restrict__ o1, float* __restrict__ o2,
                      float* __restrict__ wsproj, _Float16* __restrict__ w2h) {
    const int tid = threadIdx.x;
    const int p = blockIdx.x * 256 + tid;
    if (p < HWc) {
        const float* f = (blockIdx.y == 0) ? f0 : (blockIdx.y == 1) ? f1 : f2;
        float*       o = (blockIdx.y == 0) ? o0 : (blockIdx.y == 1) ? o1 : o2;
        float v[Cc];
#pragma unroll
        for (int c = 0; c < Cc; c++) v[c] = f[c * HWc + p];   // coalesced across lanes
        float4* o4 = (float4*)(o + (size_t)p * Cc);
#pragma unroll
        for (int j = 0; j < 8; j++)
            o4[j] = make_float4(v[4 * j], v[4 * j + 1], v[4 * j + 2], v[4 * j + 3]);
    }
    if (blockIdx.x == 0 && blockIdx.y == 0) {
        // fp16 weight repack: w2h[half(2)][khkw(9)][kd(3)][c(16)]
        for (int i = tid; i < 2 * 9 * 3 * CH; i += 256) {
            int c = i & 15;
            int t = i >> 4;          // ((hf*9+khkw)*3+kd)
            int kd = t % 3;
            int t2 = t / 3;
            int khkw = t2 % 9;
            int hf = t2 / 9;
            int ch = hf * CH + c;
            w2h[i] = (_Float16)wreg[ch * 27 + kd * 9 + khkw];
        }
        if (tid == 0) {
            float a[4][8];
            for (int i = 0; i < 4; i++)
                for (int j = 0; j < 4; j++) {
                    a[i][j]     = proj[i * 4 + j];
                    a[i][j + 4] = (i == j) ? 1.f : 0.f;
                }
            for (int col = 0; col < 4; col++) {
                int piv = col; float best = fabsf(a[col][col]);
                for (int r = col + 1; r < 4; r++) {
                    float v = fabsf(a[r][col]);
                    if (v > best) { best = v; piv = r; }
                }
                if (piv != col)
                    for (int j = 0; j < 8; j++) { float t = a[col][j]; a[col][j] = a[piv][j]; a[piv][j] = t; }
                float inv = 1.f / a[col][col];
                for (int j = 0; j < 8; j++) a[col][j] *= inv;
                for (int r = 0; r < 4; r++) if (r != col) {
                    float f = a[r][col];
                    for (int j = 0; j < 8; j++) a[r][j] -= f * a[col][j];
                }
            }
            for (int v = 1; v < 3; v++) {
                const float* P = proj + v * 16;
                float M[3][4];
                for (int i = 0; i < 3; i++)
                    for (int j = 0; j < 4; j++) {
                        float s = 0.f;
                        for (int k = 0; k < 4; k++) s += P[i * 4 + k] * a[k][4 + j];
                        M[i][j] = s;
                    }
                float* o = wsproj + (v - 1) * 12;
                o[0] = M[0][0]; o[1] = M[0][1]; o[2] = M[0][2];
                o[3] = M[1][0]; o[4] = M[1][1]; o[5] = M[1][2];
                o[6] = M[2][0]; o[7] = M[2][1]; o[8] = M[2][2];
                o[9] = M[0][3]; o[10] = M[1][3]; o[11] = M[2][3];
            }
        }
    }
}

// ---------------- kernel 2: fused warp + variance + 3D conv (per channel half) ----------------
// 256 thr, launch_bounds(256,2) (128-VGPR cap; only non-spilling config — R2/R6/R7).
// R9: fp16 var in LDS (48B/pos stride: 16-aligned, 12-bank step = 2-way free) +
// fp16 weights + v_dot2_f32_f16 conv -> conv loads 144->72/thread-slice, LDS 26KB
// -> 6 blocks/CU resource cap. DCHUNK=4 -> 1920 blocks (7.5/CU demand) so ~24
// waves/CU resident (was dispatch-limited at 3.75 blocks/CU). +20% slice work.
// Spill guard: WRITE_SIZE ~7.7MB.
__global__ __launch_bounds__(256, 2) void k_cost(
    const float* __restrict__ fT0, const float* __restrict__ fT1, const float* __restrict__ fT2,
    const float* __restrict__ dvals, const float4* __restrict__ w2h4,
    const float* __restrict__ wsproj, float* __restrict__ costA, float* __restrict__ costB)
{
    __shared__ __align__(16) char var_raw[NPOS * VSTRB];   // 15552 B
    __shared__ float4 par_l[NPOS * PSTR4];                  // 10368 B
    __shared__ float projl[24];
    float2* var2 = (float2*)var_raw;        // pos*6 + cc
    const float4* var4 = (const float4*)var_raw;  // pos*3 + {0,1}

    const int tid = threadIdx.x;
    if (tid < 24) projl[tid] = wsproj[tid];
    __syncthreads();

    const int tileX = blockIdx.x;                 // 0..9
    const int tileY = blockIdx.y;                 // 0..7
    const int hf    = blockIdx.z & 1;             // channel half
    const int d0    = (blockIdx.z >> 1) * DCHUNK;
    const int tx = tid & 15, ty = tid >> 4;
    const int baseH = tileY * TS - 1, baseW = tileX * TS - 1;

    const int posq = tid >> 2;                    // quad id (0..63): position within pass
    const int cc   = tid & 3;                     // float4 slot within half-record
    const int co   = hf * 4 + cc;                 // float4 offset into 32-ch record

    const float4* fT0_4 = (const float4*)fT0;
    const float4* fT1_4 = (const float4*)fT1;
    const float4* fT2_4 = (const float4*)fT2;

    // ---- Phase A setup: thread owns positions tid, tid+256; rays hoisted ----
    float rAx[2][2], rAy[2][2], rAz[2][2];
    float trn[2][3];
#pragma unroll
    for (int v = 0; v < 2; v++) {
        trn[v][0] = projl[v * 12 + 9];
        trn[v][1] = projl[v * 12 + 10];
        trn[v][2] = projl[v * 12 + 11];
    }
    int amask = 0;
#pragma unroll
    for (int s = 0; s < 2; s++) {
        int p = tid + s * 256;
        bool act = p < NPOS;
        int pp = act ? p : 0;
        int py = pp / HALO, px = pp % HALO;
        int hyi = baseH + py, hxi = baseW + px;
        bool ok = act && hyi >= 0 && hyi < Hc && hxi >= 0 && hxi < Wc;
        if (ok) amask |= (1 << s);
        float hx = (float)hxi, hy = (float)hyi;
#pragma unroll
        for (int v = 0; v < 2; v++) {
            const float* R = projl + v * 12;
            rAx[s][v] = fmaf(R[0], hx, fmaf(R[1], hy, R[2]));
            rAy[s][v] = fmaf(R[3], hx, fmaf(R[4], hy, R[5]));
            rAz[s][v] = fmaf(R[6], hx, fmaf(R[7], hy, R[8]));
        }
    }

    // ---- Phase B setup: per-pass validity + hoisted depth-independent ref taps ----
    int    bmask = 0;
    float4 rfv[NPASS];
#pragma unroll
    for (int s = 0; s < NPASS; s++) {
        int p = posq + s * 64;
        bool act = p < NPOS;
        int pp = act ? p : 0;
        int py = pp / HALO, px = pp % HALO;
        int hyi = baseH + py, hxi = baseW + px;
        bool ok = act && hyi >= 0 && hyi < Hc && hxi >= 0 && hxi < Wc;
        if (ok) bmask |= (1 << s);
        rfv[s] = ok ? fT0_4[(hyi * Wc + hxi) * 8 + co] : make_float4(0.f, 0.f, 0.f, 0.f);
    }

    float cost[DCHUNK];
#pragma unroll
    for (int i = 0; i < DCHUNK; i++) cost[i] = 0.f;

    const int cb = ty * HALO + tx;                // conv center position
    const int wkbase = hf * 9;                    // weight k-group base

    // ---- Phase A: bilinear params for slice dpn -> par_l (fp16 cw + u16 idx) ----
    auto phaseA = [&](int dpn) {
        const float depthN = dvals[dpn];
#pragma unroll
        for (int s = 0; s < 2; s++) {
            int p = tid + s * 256;
            if (p >= NPOS) break;
            if (!((amask >> s) & 1)) continue;
            float cw[2][4]; unsigned int pk[4];
#pragma unroll
            for (int v = 0; v < 2; v++) {
                float X = fmaf(rAx[s][v], depthN, trn[v][0]);
                float Y = fmaf(rAy[s][v], depthN, trn[v][1]);
                float Z = fmaf(rAz[s][v], depthN, trn[v][2]);
                float iz = 1.f / Z;
                float gx = X * iz, gy = Y * iz;
                float x0f = floorf(gx), y0f = floorf(gy);
                float wx = gx - x0f, wy = gy - y0f;
                int x0 = (int)x0f, y0 = (int)y0f;
                bool vx0 = (x0 >= 0) & (x0 <= Wc - 1);
                bool vx1 = (x0 + 1 >= 0) & (x0 + 1 <= Wc - 1);
                bool vy0 = (y0 >= 0) & (y0 <= Hc - 1);
                bool vy1 = (y0 + 1 >= 0) & (y0 + 1 <= Hc - 1);
                int xc0 = min(max(x0, 0), Wc - 1), xc1 = min(max(x0 + 1, 0), Wc - 1);
                int yc0 = min(max(y0, 0), Hc - 1), yc1 = min(max(y0 + 1, 0), Hc - 1);
                float ax = 1.f - wx, ay = 1.f - wy;
                cw[v][0] = (vx0 && vy0) ? ax * ay : 0.f;
                cw[v][1] = (vx1 && vy0) ? wx * ay : 0.f;
                cw[v][2] = (vx0 && vy1) ? ax * wy : 0.f;
                cw[v][3] = (vx1 && vy1) ? wx * wy : 0.f;
                unsigned int i0 = (unsigned int)(yc0 * Wc + xc0);
                unsigned int i1 = (unsigned int)(yc0 * Wc + xc1);
                unsigned int i2 = (unsigned int)(yc1 * Wc + xc0);
                unsigned int i3 = (unsigned int)(yc1 * Wc + xc1);
                pk[v * 2 + 0] = i0 | (i1 << 16);
                pk[v * 2 + 1] = i2 | (i3 << 16);
            }
            PackCW pc;
            pc.h[0] = __floats2half2_rn(cw[0][0], cw[0][1]);
            pc.h[1] = __floats2half2_rn(cw[0][2], cw[0][3]);
            pc.h[2] = __floats2half2_rn(cw[1][0], cw[1][1]);
            pc.h[3] = __floats2half2_rn(cw[1][2], cw[1][3]);
            par_l[p * PSTR4 + 0] = pc.f;
            par_l[p * PSTR4 + 1] = make_float4(__uint_as_float(pk[0]), __uint_as_float(pk[1]),
                                               __uint_as_float(pk[2]), __uint_as_float(pk[3]));
        }
    };

    const int dpFirst = (d0 == 0) ? 0 : d0 - 1;
    const int dpLast  = min(d0 + DCHUNK, Dc - 1);

    phaseA(dpFirst);
    __syncthreads();

    for (int dp = dpFirst; dp <= dpLast; dp++) {
        // ---- Phase B: gather + variance -> var_l fp16 (quad-coalesced 64B taps) ----
#pragma unroll
        for (int s = 0; s < NPASS; s++) {
            int p = posq + s * 64;
            if (p >= NPOS) continue;                 // only pass 5, posq>=4
            const int vaddr = p * 6 + cc;
            if (!((bmask >> s) & 1)) {
                var2[vaddr] = make_float2(0.f, 0.f);
                continue;
            }
            PackCW pc; pc.f = par_l[p * PSTR4 + 0];  // quad-broadcast reads
            float4 pkf = par_l[p * PSTR4 + 1];
            float2 c00 = __half22float2(pc.h[0]);
            float2 c01 = __half22float2(pc.h[1]);
            float2 c10 = __half22float2(pc.h[2]);
            float2 c11 = __half22float2(pc.h[3]);
            unsigned int u0 = __float_as_uint(pkf.x), u1 = __float_as_uint(pkf.y);
            unsigned int u2 = __float_as_uint(pkf.z), u3 = __float_as_uint(pkf.w);
            int i00 = u0 & 0xffff, i01 = u0 >> 16, i02 = u1 & 0xffff, i03 = u1 >> 16;
            int i10 = u2 & 0xffff, i11 = u2 >> 16, i12 = u3 & 0xffff, i13 = u3 >> 16;
            float4 rf  = rfv[s];
            float4 t00 = fT1_4[i00 * 8 + co];
            float4 t01 = fT1_4[i01 * 8 + co];
            float4 t10 = fT1_4[i02 * 8 + co];
            float4 t11 = fT1_4[i03 * 8 + co];
            float4 u00 = fT2_4[i10 * 8 + co];
            float4 u01 = fT2_4[i11 * 8 + co];
            float4 u10 = fT2_4[i12 * 8 + co];
            float4 u11 = fT2_4[i13 * 8 + co];
            v2f a1l = vfma2(vbc(c00.x), vlo(t00), vfma2(vbc(c00.y), vlo(t01),
                      vfma2(vbc(c01.x), vlo(t10), vbc(c01.y) * vlo(t11))));
            v2f a1h = vfma2(vbc(c00.x), vhi(t00), vfma2(vbc(c00.y), vhi(t01),
                      vfma2(vbc(c01.x), vhi(t10), vbc(c01.y) * vhi(t11))));
            v2f a2l = vfma2(vbc(c10.x), vlo(u00), vfma2(vbc(c10.y), vlo(u01),
                      vfma2(vbc(c11.x), vlo(u10), vbc(c11.y) * vlo(u11))));
            v2f a2h = vfma2(vbc(c10.x), vhi(u00), vfma2(vbc(c10.y), vhi(u01),
                      vfma2(vbc(c11.x), vhi(u10), vbc(c11.y) * vhi(u11))));
            v2f rl = vlo(rf), rh = vhi(rf);
            v2f sml = rl + a1l + a2l;
            v2f smh = rh + a1h + a2h;
            v2f sql = vfma2(a2l, a2l, vfma2(a1l, a1l, rl * rl));
            v2f sqh = vfma2(a2h, a2h, vfma2(a1h, a1h, rh * rh));
            v2f vrl = vfma2(sml * sml, vbc(-1.f / 9.f), sql * vbc(1.f / 3.f));
            v2f vrh = vfma2(smh * smh, vbc(-1.f / 9.f), sqh * vbc(1.f / 3.f));
            H2F o;
            o.h[0] = __builtin_convertvector(vrl, h2);
            o.h[1] = __builtin_convertvector(vrh, h2);
            var2[vaddr] = o.f;
        }
        __syncthreads();

        // ---- Phase A for next slice (overlaps conv latency) ----
        if (dp < dpLast) phaseA(dp + 1);

        // ---- 3x3 spatial conv via fp16 dot2: 3 kd planes, 16 channels ----
        float a0 = 0.f, a1 = 0.f, a2 = 0.f;
#pragma unroll
        for (int k = 0; k < 9; k++) {
            const int vp = (cb + (k / 3) * HALO + (k % 3)) * 3;
            F4H va, vb;
            va.f = var4[vp + 0];             // ch 0-7
            vb.f = var4[vp + 1];             // ch 8-15
            const int wb = (wkbase + k) * 6;
            F4H wa0, wb0, wa1, wb1, wa2, wb2;
            wa0.f = w2h4[wb + 0]; wb0.f = w2h4[wb + 1];
            wa1.f = w2h4[wb + 2]; wb1.f = w2h4[wb + 3];
            wa2.f = w2h4[wb + 4]; wb2.f = w2h4[wb + 5];
#pragma unroll
            for (int i = 0; i < 4; i++) {
                a0 = hdot2(va.h[i], wa0.h[i], a0);
                a0 = hdot2(vb.h[i], wb0.h[i], a0);
                a1 = hdot2(va.h[i], wa1.h[i], a1);
                a1 = hdot2(vb.h[i], wb1.h[i], a1);
                a2 = hdot2(va.h[i], wa2.h[i], a2);
                a2 = hdot2(vb.h[i], wb2.h[i], a2);
            }
        }
        // cost(d) = A0(d-1) + A1(d) + A2(d+1)
        int r;
        r = dp + 1 - d0; if (r >= 0 && r < DCHUNK) cost[r] += a0;
        r = dp - d0;     if (r >= 0 && r < DCHUNK) cost[r] += a1;
        r = dp - 1 - d0; if (r >= 0 && r < DCHUNK) cost[r] += a2;
        __syncthreads();
    }

    float* outv = hf ? costB : costA;
    const int h = tileY * TS + ty, w = tileX * TS + tx;
#pragma unroll
    for (int i = 0; i < DCHUNK; i++)
        outv[(d0 + i) * HWc + h * Wc + w] = cost[i];
}

// ---------------- kernel 3: softmax over depth + regression ----------------
__global__ void k_softmax(const float* __restrict__ costA, const float* __restrict__ costB,
                          const float* __restrict__ dvals, const float* __restrict__ breg,
                          float* __restrict__ out)
{
    const int px = blockIdx.x * 256 + threadIdx.x;
    if (px >= HWc) return;
    const float bias = breg[0];
    float c[Dc];
    float m = -1e30f;
#pragma unroll
    for (int d = 0; d < Dc; d++) {
        c[d] = costA[d * HWc + px] + costB[d * HWc + px] + bias;
        m = fmaxf(m, c[d]);
    }
    float se = 0.f, sed = 0.f, me = 0.f;
#pragma unroll
    for (int d = 0; d < Dc; d++) {
        float e = __expf(c[d] - m);
        se += e;
        sed = fmaf(e, dvals[d], sed);
        me = fmaxf(me, e);
    }
    float inv = 1.f / se;
    out[px]       = sed * inv;   // depth
    out[HWc + px] = me * inv;    // photometric confidence
}

extern "C" void kernel_launch(void* const* d_in, const int* in_sizes, int n_in,
                              void* d_out, int out_size, void* d_ws, size_t ws_size,
                              hipStream_t stream) {
    const float* f0    = (const float*)d_in[0];
    const float* f1    = (const float*)d_in[1];
    const float* f2    = (const float*)d_in[2];
    const float* proj  = (const float*)d_in[3];
    const float* dvals = (const float*)d_in[4];
    const float* wreg  = (const float*)d_in[5];
    const float* breg  = (const float*)d_in[6];

    float* ws      = (float*)d_ws;
    float* wsproj  = ws;                    // 24 floats (pad to 32)
    _Float16* w2h  = (_Float16*)(ws + 32);  // 864 fp16 = 1728 B (within 864-float slot)
    float* fT0     = ws + 896;              // 655360 floats each
    float* fT1     = fT0 + (size_t)HWc * Cc;
    float* fT2     = fT1 + (size_t)HWc * Cc;
    float* costA   = fT2 + (size_t)HWc * Cc;   // Dc*HWc floats
    float* costB   = costA + (size_t)Dc * HWc;

    k_pre<<<dim3((HWc + 255) / 256, 3), 256, 0, stream>>>(f0, f1, f2, proj, wreg,
                                                          fT0, fT1, fT2, wsproj, w2h);

    dim3 grid(Wc / TS, Hc / TS, NCHUNK * 2);   // 10 x 8 x 24 = 1920 blocks of 256
    k_cost<<<grid, 256, 0, stream>>>(fT0, fT1, fT2, dvals, (const float4*)w2h,
                                     wsproj, costA, costB);

    k_softmax<<<(HWc + 255) / 256, 256, 0, stream>>>(costA, costB, dvals, breg, (float*)d_out);
}

// Round 10
// 162.944 us; speedup vs baseline: 6.4163x; 1.2481x over previous
//
#include <hip/hip_runtime.h>
#include <hip/hip_fp16.h>
#include <math.h>

#define Cc 32
#define Hc 128
#define Wc 160
#define Dc 48
#define HWc (Hc*Wc)
#define TS 16
#define HALO (TS+2)           // 18
#define NPOS (HALO*HALO)      // 324
#define DCHUNK 4
#define NCHUNK (Dc/DCHUNK)    // 12
#define VSTR4 5               // var position stride in float4 units (64B fp16 payload + 16B pad)
#define NPASS 6               // ceil(NPOS / 64 quads)

typedef _Float16 h2 __attribute__((ext_vector_type(2)));

static __device__ __forceinline__ float hdot2(h2 a, h2 b, float acc) {
#if __has_builtin(__builtin_amdgcn_fdot2)
    return __builtin_amdgcn_fdot2(a, b, acc, false);
#else
    return fmaf((float)a.y, (float)b.y, fmaf((float)a.x, (float)b.x, acc));
#endif
}

union F4H { float4 f; __half2 h[4]; h2 d[4]; };
union PackCW { __half2 h[4]; float4 f; };

// ---------------- kernel 1: transpose CHW->HWC (fp32->fp16) + proj + fp16 weight repack ----------------
__global__ void k_pre(const float* __restrict__ f0, const float* __restrict__ f1,
                      const float* __restrict__ f2, const float* __restrict__ proj,
                      const float* __restrict__ wreg,
                      _Float16* __restrict__ o0, _Float16* __restrict__ o1, _Float16* __restrict__ o2,
                      float* __restrict__ wsproj, _Float16* __restrict__ w2h) {
    const int tid = threadIdx.x;
    const int p = blockIdx.x * 256 + tid;
    if (p < HWc) {
        const float* f = (blockIdx.y == 0) ? f0 : (blockIdx.y == 1) ? f1 : f2;
        _Float16*    o = (blockIdx.y == 0) ? o0 : (blockIdx.y == 1) ? o1 : o2;
        float v[Cc];
#pragma unroll
        for (int c = 0; c < Cc; c++) v[c] = f[c * HWc + p];   // coalesced across lanes
        union { __half2 h[16]; float4 f4[4]; } rec;
#pragma unroll
        for (int c = 0; c < 16; c++) rec.h[c] = __floats2half2_rn(v[2 * c], v[2 * c + 1]);
        float4* o4 = (float4*)(o + (size_t)p * Cc);
#pragma unroll
        for (int j = 0; j < 4; j++) o4[j] = rec.f4[j];
    }
    if (blockIdx.x == 0 && blockIdx.y == 0) {
        // fp16 weight repack: w2h[khkw(9)][kd(3)][c(32)]
        for (int i = tid; i < 9 * 3 * Cc; i += 256) {
            int ch = i & 31;
            int t  = i >> 5;         // khkw*3 + kd
            int kd = t % 3;
            int khkw = t / 3;
            w2h[i] = (_Float16)wreg[ch * 27 + kd * 9 + khkw];
        }
        if (tid == 0) {
            float a[4][8];
            for (int i = 0; i < 4; i++)
                for (int j = 0; j < 4; j++) {
                    a[i][j]     = proj[i * 4 + j];
                    a[i][j + 4] = (i == j) ? 1.f : 0.f;
                }
            for (int col = 0; col < 4; col++) {
                int piv = col; float best = fabsf(a[col][col]);
                for (int r = col + 1; r < 4; r++) {
                    float v = fabsf(a[r][col]);
                    if (v > best) { best = v; piv = r; }
                }
                if (piv != col)
                    for (int j = 0; j < 8; j++) { float t = a[col][j]; a[col][j] = a[piv][j]; a[piv][j] = t; }
                float inv = 1.f / a[col][col];
                for (int j = 0; j < 8; j++) a[col][j] *= inv;
                for (int r = 0; r < 4; r++) if (r != col) {
                    float f = a[r][col];
                    for (int j = 0; j < 8; j++) a[r][j] -= f * a[col][j];
                }
            }
            for (int v = 1; v < 3; v++) {
                const float* P = proj + v * 16;
                float M[3][4];
                for (int i = 0; i < 3; i++)
                    for (int j = 0; j < 4; j++) {
                        float s = 0.f;
                        for (int k = 0; k < 4; k++) s += P[i * 4 + k] * a[k][4 + j];
                        M[i][j] = s;
                    }
                float* o = wsproj + (v - 1) * 12;
                o[0] = M[0][0]; o[1] = M[0][1]; o[2] = M[0][2];
                o[3] = M[1][0]; o[4] = M[1][1]; o[5] = M[1][2];
                o[6] = M[2][0]; o[7] = M[2][1]; o[8] = M[2][2];
                o[9] = M[0][3]; o[10] = M[1][3]; o[11] = M[2][3];
            }
        }
    }
}

// ---------------- kernel 2: fused warp + variance + 3D conv, full 32ch per block ----------------
// 256 thr, launch_bounds(256,2) (128-VGPR cap; the only non-spilling config — R2/R6/R7).
// R10: fp16 feature records (64B = 32ch) -> one quad gather serves BOTH channel
// halves (tap instrs/tile-slice 96->48), Phase A once per tile (was 2x), blend+
// variance in v_pk_fma_f16. Grid 960 (DCHUNK=4), LDS 36.5KB -> 4 blocks/CU =
// single generation. Spill guard: WRITE_SIZE must stay ~6MB.
__global__ __launch_bounds__(256, 2) void k_cost(
    const _Float16* __restrict__ fT0, const _Float16* __restrict__ fT1,
    const _Float16* __restrict__ fT2, const float* __restrict__ dvals,
    const float4* __restrict__ w2h4, const float* __restrict__ wsproj,
    float* __restrict__ costvol)
{
    __shared__ float4 var_l[NPOS * VSTR4];   // 25920 B
    __shared__ float4 parW[NPOS];            // 5184 B (fp16 cw pack)
    __shared__ float4 parI[NPOS];            // 5184 B (u16 idx pack)
    __shared__ float projl[24];

    const int tid = threadIdx.x;
    if (tid < 24) projl[tid] = wsproj[tid];
    __syncthreads();

    const int tileX = blockIdx.x;                 // 0..9
    const int tileY = blockIdx.y;                 // 0..7
    const int d0    = blockIdx.z * DCHUNK;
    const int tx = tid & 15, ty = tid >> 4;
    const int baseH = tileY * TS - 1, baseW = tileX * TS - 1;

    const int posq = tid >> 2;                    // quad id (0..63): position within pass
    const int cc   = tid & 3;                     // float4 slot within 32-ch fp16 record

    const float4* fT0_4 = (const float4*)fT0;
    const float4* fT1_4 = (const float4*)fT1;
    const float4* fT2_4 = (const float4*)fT2;

    // ---- Phase A setup: thread owns positions tid, tid+256; rays hoisted ----
    float rAx[2][2], rAy[2][2], rAz[2][2];
    float trn[2][3];
#pragma unroll
    for (int v = 0; v < 2; v++) {
        trn[v][0] = projl[v * 12 + 9];
        trn[v][1] = projl[v * 12 + 10];
        trn[v][2] = projl[v * 12 + 11];
    }
    int amask = 0;
#pragma unroll
    for (int s = 0; s < 2; s++) {
        int p = tid + s * 256;
        bool act = p < NPOS;
        int pp = act ? p : 0;
        int py = pp / HALO, px = pp % HALO;
        int hyi = baseH + py, hxi = baseW + px;
        bool ok = act && hyi >= 0 && hyi < Hc && hxi >= 0 && hxi < Wc;
        if (ok) amask |= (1 << s);
        float hx = (float)hxi, hy = (float)hyi;
#pragma unroll
        for (int v = 0; v < 2; v++) {
            const float* R = projl + v * 12;
            rAx[s][v] = fmaf(R[0], hx, fmaf(R[1], hy, R[2]));
            rAy[s][v] = fmaf(R[3], hx, fmaf(R[4], hy, R[5]));
            rAz[s][v] = fmaf(R[6], hx, fmaf(R[7], hy, R[8]));
        }
    }

    // ---- Phase B setup: per-pass validity + hoisted depth-independent ref taps ----
    int    bmask = 0;
    float4 rfv[NPASS];
#pragma unroll
    for (int s = 0; s < NPASS; s++) {
        int p = posq + s * 64;
        bool act = p < NPOS;
        int pp = act ? p : 0;
        int py = pp / HALO, px = pp % HALO;
        int hyi = baseH + py, hxi = baseW + px;
        bool ok = act && hyi >= 0 && hyi < Hc && hxi >= 0 && hxi < Wc;
        if (ok) bmask |= (1 << s);
        rfv[s] = ok ? fT0_4[(hyi * Wc + hxi) * 4 + cc] : make_float4(0.f, 0.f, 0.f, 0.f);
    }

    float cost[DCHUNK];
#pragma unroll
    for (int i = 0; i < DCHUNK; i++) cost[i] = 0.f;

    const int cb = ty * HALO + tx;                // conv center position

    // ---- Phase A: bilinear params for slice dpn -> parW/parI ----
    auto phaseA = [&](int dpn) {
        const float depthN = dvals[dpn];
#pragma unroll
        for (int s = 0; s < 2; s++) {
            int p = tid + s * 256;
            if (p >= NPOS) break;
            if (!((amask >> s) & 1)) continue;
            float cw[2][4]; unsigned int pk[4];
#pragma unroll
            for (int v = 0; v < 2; v++) {
                float X = fmaf(rAx[s][v], depthN, trn[v][0]);
                float Y = fmaf(rAy[s][v], depthN, trn[v][1]);
                float Z = fmaf(rAz[s][v], depthN, trn[v][2]);
                float iz = 1.f / Z;
                float gx = X * iz, gy = Y * iz;
                float x0f = floorf(gx), y0f = floorf(gy);
                float wx = gx - x0f, wy = gy - y0f;
                int x0 = (int)x0f, y0 = (int)y0f;
                bool vx0 = (x0 >= 0) & (x0 <= Wc - 1);
                bool vx1 = (x0 + 1 >= 0) & (x0 + 1 <= Wc - 1);
                bool vy0 = (y0 >= 0) & (y0 <= Hc - 1);
                bool vy1 = (y0 + 1 >= 0) & (y0 + 1 <= Hc - 1);
                int xc0 = min(max(x0, 0), Wc - 1), xc1 = min(max(x0 + 1, 0), Wc - 1);
                int yc0 = min(max(y0, 0), Hc - 1), yc1 = min(max(y0 + 1, 0), Hc - 1);
                float ax = 1.f - wx, ay = 1.f - wy;
                cw[v][0] = (vx0 && vy0) ? ax * ay : 0.f;
                cw[v][1] = (vx1 && vy0) ? wx * ay : 0.f;
                cw[v][2] = (vx0 && vy1) ? ax * wy : 0.f;
                cw[v][3] = (vx1 && vy1) ? wx * wy : 0.f;
                unsigned int i0 = (unsigned int)(yc0 * Wc + xc0);
                unsigned int i1 = (unsigned int)(yc0 * Wc + xc1);
                unsigned int i2 = (unsigned int)(yc1 * Wc + xc0);
                unsigned int i3 = (unsigned int)(yc1 * Wc + xc1);
                pk[v * 2 + 0] = i0 | (i1 << 16);
                pk[v * 2 + 1] = i2 | (i3 << 16);
            }
            PackCW pc;
            pc.h[0] = __floats2half2_rn(cw[0][0], cw[0][1]);
            pc.h[1] = __floats2half2_rn(cw[0][2], cw[0][3]);
            pc.h[2] = __floats2half2_rn(cw[1][0], cw[1][1]);
            pc.h[3] = __floats2half2_rn(cw[1][2], cw[1][3]);
            parW[p] = pc.f;
            parI[p] = make_float4(__uint_as_float(pk[0]), __uint_as_float(pk[1]),
                                  __uint_as_float(pk[2]), __uint_as_float(pk[3]));
        }
    };

    const int dpFirst = (d0 == 0) ? 0 : d0 - 1;
    const int dpLast  = min(d0 + DCHUNK, Dc - 1);

    phaseA(dpFirst);
    __syncthreads();

    const __half2 kT3 = __float2half2_rn(1.f / 3.f);
    const __half2 kN9 = __float2half2_rn(-1.f / 9.f);

    for (int dp = dpFirst; dp <= dpLast; dp++) {
        // ---- Phase B: gather + variance -> var_l, all in packed fp16 ----
#pragma unroll
        for (int s = 0; s < NPASS; s++) {
            int p = posq + s * 64;
            if (p >= NPOS) continue;                 // only pass 5, posq>=4
            const int vaddr = p * VSTR4 + cc;
            if (!((bmask >> s) & 1)) {
                var_l[vaddr] = make_float4(0.f, 0.f, 0.f, 0.f);
                continue;
            }
            PackCW pc; pc.f = parW[p];               // quad-broadcast reads
            float4 pkf = parI[p];
            __half2 c0a = __low2half2(pc.h[0]), c0b = __high2half2(pc.h[0]);
            __half2 c0c = __low2half2(pc.h[1]), c0d = __high2half2(pc.h[1]);
            __half2 c1a = __low2half2(pc.h[2]), c1b = __high2half2(pc.h[2]);
            __half2 c1c = __low2half2(pc.h[3]), c1d = __high2half2(pc.h[3]);
            unsigned int u0 = __float_as_uint(pkf.x), u1 = __float_as_uint(pkf.y);
            unsigned int u2 = __float_as_uint(pkf.z), u3 = __float_as_uint(pkf.w);
            int i00 = u0 & 0xffff, i01 = u0 >> 16, i02 = u1 & 0xffff, i03 = u1 >> 16;
            int i10 = u2 & 0xffff, i11 = u2 >> 16, i12 = u3 & 0xffff, i13 = u3 >> 16;
            F4H rf; rf.f = rfv[s];
            F4H t00, t01, t10, t11, u00v, u01v, u10v, u11v, vo;
            t00.f = fT1_4[i00 * 4 + cc];
            t01.f = fT1_4[i01 * 4 + cc];
            t10.f = fT1_4[i02 * 4 + cc];
            t11.f = fT1_4[i03 * 4 + cc];
            u00v.f = fT2_4[i10 * 4 + cc];
            u01v.f = fT2_4[i11 * 4 + cc];
            u10v.f = fT2_4[i12 * 4 + cc];
            u11v.f = fT2_4[i13 * 4 + cc];
#pragma unroll
            for (int j = 0; j < 4; j++) {
                __half2 a1 = __hfma2(c0a, t00.h[j], __hfma2(c0b, t01.h[j],
                             __hfma2(c0c, t10.h[j], __hmul2(c0d, t11.h[j]))));
                __half2 a2 = __hfma2(c1a, u00v.h[j], __hfma2(c1b, u01v.h[j],
                             __hfma2(c1c, u10v.h[j], __hmul2(c1d, u11v.h[j]))));
                __half2 r  = rf.h[j];
                __half2 sm = __hadd2(r, __hadd2(a1, a2));
                __half2 sq = __hfma2(r, r, __hfma2(a1, a1, __hmul2(a2, a2)));
                vo.h[j] = __hfma2(__hmul2(sm, sm), kN9, __hmul2(sq, kT3));
            }
            var_l[vaddr] = vo.f;
        }
        __syncthreads();

        // ---- Phase A for next slice (overlaps conv latency) ----
        if (dp < dpLast) phaseA(dp + 1);

        // ---- 3x3 spatial conv via fp16 dot2: 3 kd planes, 32 channels ----
        float a0 = 0.f, a1 = 0.f, a2 = 0.f;
#pragma unroll
        for (int k = 0; k < 9; k++) {
            const int vp = (cb + (k / 3) * HALO + (k % 3)) * VSTR4;
            F4H va[4];
#pragma unroll
            for (int j = 0; j < 4; j++) va[j].f = var_l[vp + j];
            const int wb = k * 12;                   // float4 units: (k*3+kd)*4
#pragma unroll
            for (int j = 0; j < 4; j++) {
                F4H w0, w1, w2v;
                w0.f  = w2h4[wb + 0 + j];
                w1.f  = w2h4[wb + 4 + j];
                w2v.f = w2h4[wb + 8 + j];
#pragma unroll
                for (int i = 0; i < 4; i++) {
                    a0 = hdot2(va[j].d[i], w0.d[i], a0);
                    a1 = hdot2(va[j].d[i], w1.d[i], a1);
                    a2 = hdot2(va[j].d[i], w2v.d[i], a2);
                }
            }
        }
        // cost(d) = A0(d-1) + A1(d) + A2(d+1)
        int r;
        r = dp + 1 - d0; if (r >= 0 && r < DCHUNK) cost[r] += a0;
        r = dp - d0;     if (r >= 0 && r < DCHUNK) cost[r] += a1;
        r = dp - 1 - d0; if (r >= 0 && r < DCHUNK) cost[r] += a2;
        __syncthreads();
    }

    const int h = tileY * TS + ty, w = tileX * TS + tx;
#pragma unroll
    for (int i = 0; i < DCHUNK; i++)
        costvol[(d0 + i) * HWc + h * Wc + w] = cost[i];
}

// ---------------- kernel 3: softmax over depth + regression ----------------
__global__ void k_softmax(const float* __restrict__ costvol, const float* __restrict__ dvals,
                          const float* __restrict__ breg, float* __restrict__ out)
{
    const int px = blockIdx.x * 256 + threadIdx.x;
    if (px >= HWc) return;
    const float bias = breg[0];
    float c[Dc];
    float m = -1e30f;
#pragma unroll
    for (int d = 0; d < Dc; d++) {
        c[d] = costvol[d * HWc + px] + bias;
        m = fmaxf(m, c[d]);
    }
    float se = 0.f, sed = 0.f, me = 0.f;
#pragma unroll
    for (int d = 0; d < Dc; d++) {
        float e = __expf(c[d] - m);
        se += e;
        sed = fmaf(e, dvals[d], sed);
        me = fmaxf(me, e);
    }
    float inv = 1.f / se;
    out[px]       = sed * inv;   // depth
    out[HWc + px] = me * inv;    // photometric confidence
}

extern "C" void kernel_launch(void* const* d_in, const int* in_sizes, int n_in,
                              void* d_out, int out_size, void* d_ws, size_t ws_size,
                              hipStream_t stream) {
    const float* f0    = (const float*)d_in[0];
    const float* f1    = (const float*)d_in[1];
    const float* f2    = (const float*)d_in[2];
    const float* proj  = (const float*)d_in[3];
    const float* dvals = (const float*)d_in[4];
    const float* wreg  = (const float*)d_in[5];
    const float* breg  = (const float*)d_in[6];

    float* ws      = (float*)d_ws;
    float* wsproj  = ws;                         // 24 floats (pad to 32)
    _Float16* w2h  = (_Float16*)(ws + 32);       // 864 fp16 = 432 float slots
    _Float16* fT0h = (_Float16*)(ws + 32 + 432); // HWc*32 fp16 = 1.31MB each
    _Float16* fT1h = fT0h + (size_t)HWc * Cc;
    _Float16* fT2h = fT1h + (size_t)HWc * Cc;
    float* costvol = (float*)(fT2h + (size_t)HWc * Cc);  // Dc*HWc floats

    k_pre<<<dim3((HWc + 255) / 256, 3), 256, 0, stream>>>(f0, f1, f2, proj, wreg,
                                                          fT0h, fT1h, fT2h, wsproj, w2h);

    dim3 grid(Wc / TS, Hc / TS, NCHUNK);   // 10 x 8 x 12 = 960 blocks of 256
    k_cost<<<grid, 256, 0, stream>>>(fT0h, fT1h, fT2h, dvals, (const float4*)w2h,
                                     wsproj, costvol);

    k_softmax<<<(HWc + 255) / 256, 256, 0, stream>>>(costvol, dvals, breg, (float*)d_out);
}

// Round 11
// 136.156 us; speedup vs baseline: 7.6786x; 1.1967x over previous
//
#include <hip/hip_runtime.h>
#include <hip/hip_fp16.h>
#include <math.h>

#define Cc 32
#define Hc 128
#define Wc 160
#define Dc 48
#define HWc (Hc*Wc)
#define TS 16
#define HALO (TS+2)           // 18
#define NPOS (HALO*HALO)      // 324
#define DCHUNK 3
#define NCHUNK (Dc/DCHUNK)    // 16
#define VSTR4 5               // var position stride in float4 units (64B fp16 payload + 16B pad)
#define NPASS 6               // ceil(NPOS / 64 quads)

typedef _Float16 h2 __attribute__((ext_vector_type(2)));

static __device__ __forceinline__ float hdot2(h2 a, h2 b, float acc) {
#if __has_builtin(__builtin_amdgcn_fdot2)
    return __builtin_amdgcn_fdot2(a, b, acc, false);
#else
    return fmaf((float)a.y, (float)b.y, fmaf((float)a.x, (float)b.x, acc));
#endif
}

union F4H { float4 f; __half2 h[4]; h2 d[4]; };
union PackCW { __half2 h[4]; float4 f; };

// ---------------- kernel 1: transpose CHW->HWC (fp32->fp16) + proj + weights + costvol zero ----------------
__global__ void k_pre(const float* __restrict__ f0, const float* __restrict__ f1,
                      const float* __restrict__ f2, const float* __restrict__ proj,
                      const float* __restrict__ wreg,
                      _Float16* __restrict__ o0, _Float16* __restrict__ o1, _Float16* __restrict__ o2,
                      float* __restrict__ wsproj, _Float16* __restrict__ w2h,
                      float* __restrict__ costvol) {
    const int tid = threadIdx.x;
    const int p = blockIdx.x * 256 + tid;
    if (blockIdx.y == 3) {
        // zero costvol for atomic accumulation (ws is poisoned 0xAA each call)
        if (p < HWc) {
#pragma unroll
            for (int d = 0; d < Dc; d++) costvol[d * HWc + p] = 0.f;
        }
        return;
    }
    if (p < HWc) {
        const float* f = (blockIdx.y == 0) ? f0 : (blockIdx.y == 1) ? f1 : f2;
        _Float16*    o = (blockIdx.y == 0) ? o0 : (blockIdx.y == 1) ? o1 : o2;
        float v[Cc];
#pragma unroll
        for (int c = 0; c < Cc; c++) v[c] = f[c * HWc + p];   // coalesced across lanes
        union { __half2 h[16]; float4 f4[4]; } rec;
#pragma unroll
        for (int c = 0; c < 16; c++) rec.h[c] = __floats2half2_rn(v[2 * c], v[2 * c + 1]);
        float4* o4 = (float4*)(o + (size_t)p * Cc);
#pragma unroll
        for (int j = 0; j < 4; j++) o4[j] = rec.f4[j];
    }
    if (blockIdx.x == 0 && blockIdx.y == 0) {
        // fp16 weight repack: w2h[khkw(9)][kd(3)][c(32)]
        for (int i = tid; i < 9 * 3 * Cc; i += 256) {
            int ch = i & 31;
            int t  = i >> 5;         // khkw*3 + kd
            int kd = t % 3;
            int khkw = t / 3;
            w2h[i] = (_Float16)wreg[ch * 27 + kd * 9 + khkw];
        }
        if (tid == 0) {
            float a[4][8];
            for (int i = 0; i < 4; i++)
                for (int j = 0; j < 4; j++) {
                    a[i][j]     = proj[i * 4 + j];
                    a[i][j + 4] = (i == j) ? 1.f : 0.f;
                }
            for (int col = 0; col < 4; col++) {
                int piv = col; float best = fabsf(a[col][col]);
                for (int r = col + 1; r < 4; r++) {
                    float v = fabsf(a[r][col]);
                    if (v > best) { best = v; piv = r; }
                }
                if (piv != col)
                    for (int j = 0; j < 8; j++) { float t = a[col][j]; a[col][j] = a[piv][j]; a[piv][j] = t; }
                float inv = 1.f / a[col][col];
                for (int j = 0; j < 8; j++) a[col][j] *= inv;
                for (int r = 0; r < 4; r++) if (r != col) {
                    float f = a[r][col];
                    for (int j = 0; j < 8; j++) a[r][j] -= f * a[col][j];
                }
            }
            for (int v = 1; v < 3; v++) {
                const float* P = proj + v * 16;
                float M[3][4];
                for (int i = 0; i < 3; i++)
                    for (int j = 0; j < 4; j++) {
                        float s = 0.f;
                        for (int k = 0; k < 4; k++) s += P[i * 4 + k] * a[k][4 + j];
                        M[i][j] = s;
                    }
                float* o = wsproj + (v - 1) * 12;
                o[0] = M[0][0]; o[1] = M[0][1]; o[2] = M[0][2];
                o[3] = M[1][0]; o[4] = M[1][1]; o[5] = M[1][2];
                o[6] = M[2][0]; o[7] = M[2][1]; o[8] = M[2][2];
                o[9] = M[0][3]; o[10] = M[1][3]; o[11] = M[2][3];
            }
        }
    }
}

// ---------------- kernel 2: fused warp + variance + 3D conv, no depth halo ----------------
// 256 thr, launch_bounds(256,2) (128-VGPR cap; the only non-spilling config — R2/R6/R7).
// R11: depth-halo eliminated. Each block computes ONLY its DCHUNK slices; the
// kd-plane contributions that land outside the chunk (a2 of first slice, a0 of
// last) are atomicAdd'ed into the neighbor chunk's output. Total slice work is
// exactly Dc slices/tile (was Dc*1.5 at DCHUNK=4-with-halo). DCHUNK=3 -> grid
// 1280 blocks = 5/CU demand >= LDS cap 4/CU -> saturated 16 waves/CU.
// costvol is pre-zeroed by k_pre y==3. Spill guard: WRITE_SIZE < 30MB.
__global__ __launch_bounds__(256, 2) void k_cost(
    const _Float16* __restrict__ fT0, const _Float16* __restrict__ fT1,
    const _Float16* __restrict__ fT2, const float* __restrict__ dvals,
    const float4* __restrict__ w2h4, const float* __restrict__ wsproj,
    float* __restrict__ costvol)
{
    __shared__ float4 var_l[NPOS * VSTR4];   // 25920 B
    __shared__ float4 parW[NPOS];            // 5184 B (fp16 cw pack)
    __shared__ float4 parI[NPOS];            // 5184 B (u16 idx pack)
    __shared__ float projl[24];

    const int tid = threadIdx.x;
    if (tid < 24) projl[tid] = wsproj[tid];
    __syncthreads();

    const int tileX = blockIdx.x;                 // 0..9
    const int tileY = blockIdx.y;                 // 0..7
    const int d0    = blockIdx.z * DCHUNK;
    const int tx = tid & 15, ty = tid >> 4;
    const int baseH = tileY * TS - 1, baseW = tileX * TS - 1;

    const int posq = tid >> 2;                    // quad id (0..63): position within pass
    const int cc   = tid & 3;                     // float4 slot within 32-ch fp16 record

    const float4* fT0_4 = (const float4*)fT0;
    const float4* fT1_4 = (const float4*)fT1;
    const float4* fT2_4 = (const float4*)fT2;

    // ---- Phase A setup: thread owns positions tid, tid+256; rays hoisted ----
    float rAx[2][2], rAy[2][2], rAz[2][2];
    float trn[2][3];
#pragma unroll
    for (int v = 0; v < 2; v++) {
        trn[v][0] = projl[v * 12 + 9];
        trn[v][1] = projl[v * 12 + 10];
        trn[v][2] = projl[v * 12 + 11];
    }
    int amask = 0;
#pragma unroll
    for (int s = 0; s < 2; s++) {
        int p = tid + s * 256;
        bool act = p < NPOS;
        int pp = act ? p : 0;
        int py = pp / HALO, px = pp % HALO;
        int hyi = baseH + py, hxi = baseW + px;
        bool ok = act && hyi >= 0 && hyi < Hc && hxi >= 0 && hxi < Wc;
        if (ok) amask |= (1 << s);
        float hx = (float)hxi, hy = (float)hyi;
#pragma unroll
        for (int v = 0; v < 2; v++) {
            const float* R = projl + v * 12;
            rAx[s][v] = fmaf(R[0], hx, fmaf(R[1], hy, R[2]));
            rAy[s][v] = fmaf(R[3], hx, fmaf(R[4], hy, R[5]));
            rAz[s][v] = fmaf(R[6], hx, fmaf(R[7], hy, R[8]));
        }
    }

    // ---- Phase B setup: per-pass validity + hoisted depth-independent ref taps ----
    int    bmask = 0;
    float4 rfv[NPASS];
#pragma unroll
    for (int s = 0; s < NPASS; s++) {
        int p = posq + s * 64;
        bool act = p < NPOS;
        int pp = act ? p : 0;
        int py = pp / HALO, px = pp % HALO;
        int hyi = baseH + py, hxi = baseW + px;
        bool ok = act && hyi >= 0 && hyi < Hc && hxi >= 0 && hxi < Wc;
        if (ok) bmask |= (1 << s);
        rfv[s] = ok ? fT0_4[(hyi * Wc + hxi) * 4 + cc] : make_float4(0.f, 0.f, 0.f, 0.f);
    }

    float cost[DCHUNK];
#pragma unroll
    for (int i = 0; i < DCHUNK; i++) cost[i] = 0.f;
    float bndLo = 0.f, bndHi = 0.f;               // contributions crossing chunk edges

    const int cb = ty * HALO + tx;                // conv center position

    // ---- Phase A: bilinear params for slice dpn -> parW/parI ----
    auto phaseA = [&](int dpn) {
        const float depthN = dvals[dpn];
#pragma unroll
        for (int s = 0; s < 2; s++) {
            int p = tid + s * 256;
            if (p >= NPOS) break;
            if (!((amask >> s) & 1)) continue;
            float cw[2][4]; unsigned int pk[4];
#pragma unroll
            for (int v = 0; v < 2; v++) {
                float X = fmaf(rAx[s][v], depthN, trn[v][0]);
                float Y = fmaf(rAy[s][v], depthN, trn[v][1]);
                float Z = fmaf(rAz[s][v], depthN, trn[v][2]);
                float iz = 1.f / Z;
                float gx = X * iz, gy = Y * iz;
                float x0f = floorf(gx), y0f = floorf(gy);
                float wx = gx - x0f, wy = gy - y0f;
                int x0 = (int)x0f, y0 = (int)y0f;
                bool vx0 = (x0 >= 0) & (x0 <= Wc - 1);
                bool vx1 = (x0 + 1 >= 0) & (x0 + 1 <= Wc - 1);
                bool vy0 = (y0 >= 0) & (y0 <= Hc - 1);
                bool vy1 = (y0 + 1 >= 0) & (y0 + 1 <= Hc - 1);
                int xc0 = min(max(x0, 0), Wc - 1), xc1 = min(max(x0 + 1, 0), Wc - 1);
                int yc0 = min(max(y0, 0), Hc - 1), yc1 = min(max(y0 + 1, 0), Hc - 1);
                float ax = 1.f - wx, ay = 1.f - wy;
                cw[v][0] = (vx0 && vy0) ? ax * ay : 0.f;
                cw[v][1] = (vx1 && vy0) ? wx * ay : 0.f;
                cw[v][2] = (vx0 && vy1) ? ax * wy : 0.f;
                cw[v][3] = (vx1 && vy1) ? wx * wy : 0.f;
                unsigned int i0 = (unsigned int)(yc0 * Wc + xc0);
                unsigned int i1 = (unsigned int)(yc0 * Wc + xc1);
                unsigned int i2 = (unsigned int)(yc1 * Wc + xc0);
                unsigned int i3 = (unsigned int)(yc1 * Wc + xc1);
                pk[v * 2 + 0] = i0 | (i1 << 16);
                pk[v * 2 + 1] = i2 | (i3 << 16);
            }
            PackCW pc;
            pc.h[0] = __floats2half2_rn(cw[0][0], cw[0][1]);
            pc.h[1] = __floats2half2_rn(cw[0][2], cw[0][3]);
            pc.h[2] = __floats2half2_rn(cw[1][0], cw[1][1]);
            pc.h[3] = __floats2half2_rn(cw[1][2], cw[1][3]);
            parW[p] = pc.f;
            parI[p] = make_float4(__uint_as_float(pk[0]), __uint_as_float(pk[1]),
                                  __uint_as_float(pk[2]), __uint_as_float(pk[3]));
        }
    };

    const int dpFirst = d0;
    const int dpLast  = d0 + DCHUNK - 1;          // no depth halo

    phaseA(dpFirst);
    __syncthreads();

    const __half2 kT3 = __float2half2_rn(1.f / 3.f);
    const __half2 kN9 = __float2half2_rn(-1.f / 9.f);

    for (int dp = dpFirst; dp <= dpLast; dp++) {
        // ---- Phase B: gather + variance -> var_l, all in packed fp16 ----
#pragma unroll
        for (int s = 0; s < NPASS; s++) {
            int p = posq + s * 64;
            if (p >= NPOS) continue;                 // only pass 5, posq>=4
            const int vaddr = p * VSTR4 + cc;
            if (!((bmask >> s) & 1)) {
                var_l[vaddr] = make_float4(0.f, 0.f, 0.f, 0.f);
                continue;
            }
            PackCW pc; pc.f = parW[p];               // quad-broadcast reads
            float4 pkf = parI[p];
            __half2 c0a = __low2half2(pc.h[0]), c0b = __high2half2(pc.h[0]);
            __half2 c0c = __low2half2(pc.h[1]), c0d = __high2half2(pc.h[1]);
            __half2 c1a = __low2half2(pc.h[2]), c1b = __high2half2(pc.h[2]);
            __half2 c1c = __low2half2(pc.h[3]), c1d = __high2half2(pc.h[3]);
            unsigned int u0 = __float_as_uint(pkf.x), u1 = __float_as_uint(pkf.y);
            unsigned int u2 = __float_as_uint(pkf.z), u3 = __float_as_uint(pkf.w);
            int i00 = u0 & 0xffff, i01 = u0 >> 16, i02 = u1 & 0xffff, i03 = u1 >> 16;
            int i10 = u2 & 0xffff, i11 = u2 >> 16, i12 = u3 & 0xffff, i13 = u3 >> 16;
            F4H rf; rf.f = rfv[s];
            F4H t00, t01, t10, t11, u00v, u01v, u10v, u11v, vo;
            t00.f = fT1_4[i00 * 4 + cc];
            t01.f = fT1_4[i01 * 4 + cc];
            t10.f = fT1_4[i02 * 4 + cc];
            t11.f = fT1_4[i03 * 4 + cc];
            u00v.f = fT2_4[i10 * 4 + cc];
            u01v.f = fT2_4[i11 * 4 + cc];
            u10v.f = fT2_4[i12 * 4 + cc];
            u11v.f = fT2_4[i13 * 4 + cc];
#pragma unroll
            for (int j = 0; j < 4; j++) {
                __half2 a1 = __hfma2(c0a, t00.h[j], __hfma2(c0b, t01.h[j],
                             __hfma2(c0c, t10.h[j], __hmul2(c0d, t11.h[j]))));
                __half2 a2 = __hfma2(c1a, u00v.h[j], __hfma2(c1b, u01v.h[j],
                             __hfma2(c1c, u10v.h[j], __hmul2(c1d, u11v.h[j]))));
                __half2 r  = rf.h[j];
                __half2 sm = __hadd2(r, __hadd2(a1, a2));
                __half2 sq = __hfma2(r, r, __hfma2(a1, a1, __hmul2(a2, a2)));
                vo.h[j] = __hfma2(__hmul2(sm, sm), kN9, __hmul2(sq, kT3));
            }
            var_l[vaddr] = vo.f;
        }
        __syncthreads();

        // ---- Phase A for next slice (overlaps conv latency) ----
        if (dp < dpLast) phaseA(dp + 1);

        // ---- 3x3 spatial conv via fp16 dot2: 3 kd planes, 32 channels ----
        float a0 = 0.f, a1 = 0.f, a2 = 0.f;
#pragma unroll
        for (int k = 0; k < 9; k++) {
            const int vp = (cb + (k / 3) * HALO + (k % 3)) * VSTR4;
            F4H va[4];
#pragma unroll
            for (int j = 0; j < 4; j++) va[j].f = var_l[vp + j];
            const int wb = k * 12;                   // float4 units: (k*3+kd)*4
#pragma unroll
            for (int j = 0; j < 4; j++) {
                F4H w0, w1, w2v;
                w0.f  = w2h4[wb + 0 + j];
                w1.f  = w2h4[wb + 4 + j];
                w2v.f = w2h4[wb + 8 + j];
#pragma unroll
                for (int i = 0; i < 4; i++) {
                    a0 = hdot2(va[j].d[i], w0.d[i], a0);
                    a1 = hdot2(va[j].d[i], w1.d[i], a1);
                    a2 = hdot2(va[j].d[i], w2v.d[i], a2);
                }
            }
        }
        // contributions: a0 -> cost[dp+1], a1 -> cost[dp], a2 -> cost[dp-1]
        cost[dp - d0] += a1;
        int r0 = dp + 1 - d0;
        if (r0 < DCHUNK) cost[r0] += a0; else bndHi = a0;
        int r2 = dp - 1 - d0;
        if (r2 >= 0) cost[r2] += a2; else bndLo = a2;
        __syncthreads();
    }

    // ---- accumulate into global costvol (pre-zeroed; neighbors also add) ----
    const int h = tileY * TS + ty, w = tileX * TS + tx;
    float* base = costvol + h * Wc + w;
#pragma unroll
    for (int i = 0; i < DCHUNK; i++)
        atomicAdd(base + (size_t)(d0 + i) * HWc, cost[i]);
    if (d0 > 0)            atomicAdd(base + (size_t)(d0 - 1) * HWc, bndLo);
    if (d0 + DCHUNK < Dc)  atomicAdd(base + (size_t)(d0 + DCHUNK) * HWc, bndHi);
}

// ---------------- kernel 3: softmax over depth + regression ----------------
__global__ void k_softmax(const float* __restrict__ costvol, const float* __restrict__ dvals,
                          const float* __restrict__ breg, float* __restrict__ out)
{
    const int px = blockIdx.x * 256 + threadIdx.x;
    if (px >= HWc) return;
    const float bias = breg[0];
    float c[Dc];
    float m = -1e30f;
#pragma unroll
    for (int d = 0; d < Dc; d++) {
        c[d] = costvol[d * HWc + px] + bias;
        m = fmaxf(m, c[d]);
    }
    float se = 0.f, sed = 0.f, me = 0.f;
#pragma unroll
    for (int d = 0; d < Dc; d++) {
        float e = __expf(c[d] - m);
        se += e;
        sed = fmaf(e, dvals[d], sed);
        me = fmaxf(me, e);
    }
    float inv = 1.f / se;
    out[px]       = sed * inv;   // depth
    out[HWc + px] = me * inv;    // photometric confidence
}

extern "C" void kernel_launch(void* const* d_in, const int* in_sizes, int n_in,
                              void* d_out, int out_size, void* d_ws, size_t ws_size,
                              hipStream_t stream) {
    const float* f0    = (const float*)d_in[0];
    const float* f1    = (const float*)d_in[1];
    const float* f2    = (const float*)d_in[2];
    const float* proj  = (const float*)d_in[3];
    const float* dvals = (const float*)d_in[4];
    const float* wreg  = (const float*)d_in[5];
    const float* breg  = (const float*)d_in[6];

    float* ws      = (float*)d_ws;
    float* wsproj  = ws;                         // 24 floats (pad to 32)
    _Float16* w2h  = (_Float16*)(ws + 32);       // 864 fp16 = 432 float slots
    _Float16* fT0h = (_Float16*)(ws + 32 + 432); // HWc*32 fp16 = 1.31MB each
    _Float16* fT1h = fT0h + (size_t)HWc * Cc;
    _Float16* fT2h = fT1h + (size_t)HWc * Cc;
    float* costvol = (float*)(fT2h + (size_t)HWc * Cc);  // Dc*HWc floats

    k_pre<<<dim3((HWc + 255) / 256, 4), 256, 0, stream>>>(f0, f1, f2, proj, wreg,
                                                          fT0h, fT1h, fT2h, wsproj, w2h,
                                                          costvol);

    dim3 grid(Wc / TS, Hc / TS, NCHUNK);   // 10 x 8 x 16 = 1280 blocks of 256
    k_cost<<<grid, 256, 0, stream>>>(fT0h, fT1h, fT2h, dvals, (const float4*)w2h,
                                     wsproj, costvol);

    k_softmax<<<(HWc + 255) / 256, 256, 0, stream>>>(costvol, dvals, breg, (float*)d_out);
}